// Round 6
// baseline (516.061 us; speedup 1.0000x reference)
//
#include <hip/hip_runtime.h>

#define N_NODES 100000
#define N_EDGES 600000
#define IN_DIM 128
#define EDGE_DIM 32
#define HIDDEN 128
#define NUM_CLASSES 2
#define NBLK 391  // ceil(N_NODES/256)

typedef __attribute__((ext_vector_type(4))) float f32x4;
typedef _Float16 f16x2 __attribute__((ext_vector_type(2)));
typedef _Float16 f16x4 __attribute__((ext_vector_type(4)));
typedef _Float16 f16x8 __attribute__((ext_vector_type(8)));

// ===========================================================================
// CSR build
// ===========================================================================
__global__ void hist_kernel(const int* __restrict__ dst, int* __restrict__ cnt) {
    int e = blockIdx.x * blockDim.x + threadIdx.x;
    if (e < N_EDGES) atomicAdd(&cnt[dst[e]], 1);
}

__global__ void scan1_kernel(const int* __restrict__ cnt,
                             int* __restrict__ scanout, int* __restrict__ bsum) {
    __shared__ int s[256];
    int tid = threadIdx.x;
    int i = blockIdx.x * 256 + tid;
    int v = (i < N_NODES) ? cnt[i] : 0;
    s[tid] = v;
    __syncthreads();
#pragma unroll
    for (int off = 1; off < 256; off <<= 1) {
        int t = 0;
        if (tid >= off) t = s[tid - off];
        __syncthreads();
        if (tid >= off) s[tid] += t;
        __syncthreads();
    }
    if (i < N_NODES) scanout[i] = s[tid];
    if (tid == 255) bsum[blockIdx.x] = s[255];
}

__global__ void scan2_kernel(int* __restrict__ bsum) {
    __shared__ int s[512];
    int tid = threadIdx.x;
    int v = (tid < NBLK) ? bsum[tid] : 0;
    s[tid] = v;
    __syncthreads();
#pragma unroll
    for (int off = 1; off < 512; off <<= 1) {
        int t = 0;
        if (tid >= off) t = s[tid - off];
        __syncthreads();
        if (tid >= off) s[tid] += t;
        __syncthreads();
    }
    if (tid < NBLK) bsum[tid] = s[tid] - v;  // exclusive
}

__global__ void scan3_kernel(const int* __restrict__ cnt,
                             const int* __restrict__ scanout,
                             const int* __restrict__ bsum,
                             int* __restrict__ rowptr, int* __restrict__ cur) {
    int i = blockIdx.x * 256 + threadIdx.x;
    if (i < N_NODES) {
        int excl = scanout[i] + bsum[i >> 8] - cnt[i];
        rowptr[i] = excl;
        cur[i] = excl;
    }
    if (i == 0) rowptr[N_NODES] = N_EDGES;
}

// pk[pos] = { src, edge id } ; pdst[pos] = dst
__global__ void fill_kernel(const int* __restrict__ src, const int* __restrict__ dst,
                            int* __restrict__ cur, int2* __restrict__ pk,
                            int* __restrict__ pdst) {
    int e = blockIdx.x * blockDim.x + threadIdx.x;
    if (e < N_EDGES) {
        int d = dst[e];
        int pos = atomicAdd(&cur[d], 1);
        int2 v;
        v.x = src[e];
        v.y = e;
        pk[pos] = v;
        pdst[pos] = d;
    }
}

// ===========================================================================
// x -> fp16 copy
// ===========================================================================
__global__ void xb_kernel(const float* __restrict__ x, _Float16* __restrict__ xb) {
    int i = blockIdx.x * 256 + threadIdx.x;  // over N*H/2 float2
    if (i < N_NODES * HIDDEN / 2) {
        float2 v = ((const float2*)x)[i];
        f16x2 o;
        o.x = (_Float16)v.x;
        o.y = (_Float16)v.y;
        *(f16x2*)&xb[i * 2] = o;
    }
}

// ===========================================================================
// Both layers batched: WeWl = We @ Wl (32x128), beWl = be @ Wl (128)
// ===========================================================================
__global__ void wewl2_kernel(const float* __restrict__ We1, const float* __restrict__ be1,
                             const float* __restrict__ Wl1,
                             const float* __restrict__ We2, const float* __restrict__ be2,
                             const float* __restrict__ Wl2,
                             float* __restrict__ WeWl1, float* __restrict__ beWl1,
                             float* __restrict__ WeWl2, float* __restrict__ beWl2) {
    int idx0 = blockIdx.x * 256 + threadIdx.x;
    if (idx0 >= 2 * 33 * 128) return;
    int layer = idx0 >= 33 * 128;
    int idx = idx0 - layer * 33 * 128;
    const float* We = layer ? We2 : We1;
    const float* be = layer ? be2 : be1;
    const float* Wl = layer ? Wl2 : Wl1;
    float* WeWl = layer ? WeWl2 : WeWl1;
    float* beWl = layer ? beWl2 : beWl1;
    int r = idx >> 7;
    int n = idx & 127;
    float s = 0.f;
    if (r < 32) {
        for (int j = 0; j < 128; ++j) s += We[r * 128 + j] * Wl[j * 128 + n];
        WeWl[r * 128 + n] = s;
    } else {
        for (int j = 0; j < 128; ++j) s += be[j] * Wl[j * 128 + n];
        beWl[n] = s;
    }
}

// ===========================================================================
// Both layers batched: Wbig = [Wl;Wr;WeWl] -> fp16 MFMA B-frag order, K=288.
// ===========================================================================
__global__ void wbig2_kernel(const float* __restrict__ Wl1, const float* __restrict__ Wr1,
                             const float* __restrict__ WeWl1, _Float16* __restrict__ Wbs1,
                             const float* __restrict__ Wl2, const float* __restrict__ Wr2,
                             const float* __restrict__ WeWl2, _Float16* __restrict__ Wbs2) {
    int idx0 = blockIdx.x * 256 + threadIdx.x;
    if (idx0 >= 2 * 36864) return;
    int layer = idx0 >= 36864;
    int idx = idx0 - layer * 36864;
    const float* Wl = layer ? Wl2 : Wl1;
    const float* Wr = layer ? Wr2 : Wr1;
    const float* WeWl = layer ? WeWl2 : WeWl1;
    _Float16* Wbs = layer ? Wbs2 : Wbs1;
    int j = idx & 7;
    int lane = (idx >> 3) & 63;
    int rem = idx >> 9;  // 0..71
    int ks = rem % 9;
    int nt = rem / 9;
    int k = ks * 32 + ((lane >> 4) & 3) * 8 + j;
    int n = nt * 16 + (lane & 15);
    float v = (k < 128) ? Wl[k * 128 + n]
            : (k < 256) ? Wr[(k - 128) * 128 + n]
                        : WeWl[(k - 256) * 128 + n];
    Wbs[idx] = (_Float16)v;
}

// ===========================================================================
// Per-wave VGPR aggregation, wide-issue (round-2 structure, VGPR~60 so
// 8 waves/SIMD — the gather phase needs this concurrency; do NOT fuse
// with the MFMA GEMM, fusion drops occupancy 35%->18% and regresses).
// ===========================================================================
template <bool EA>
__global__ __launch_bounds__(256) void agg_kernel_t(const _Float16* __restrict__ xin,
                                                    const int* __restrict__ rowptr,
                                                    const int2* __restrict__ pk,
                                                    const float* __restrict__ ea,
                                                    _Float16* __restrict__ meanb,
                                                    _Float16* __restrict__ eamb) {
    int wid = blockIdx.x * 4 + (threadIdx.x >> 6);
    int lane = threadIdx.x & 63;
    int node = lane >> 3;
    int slot = lane & 7;
    int half = lane >> 5;   // EA path
    int k = lane & 31;      // EA path
    int n0 = wid * 8;       // N_NODES % 8 == 0, no tail guard needed

    int rp = rowptr[n0 + (lane < 9 ? lane : 8)];
    int s_n = __shfl(rp, node);
    int e_n = __shfl(rp, node + 1);
    int c_n = e_n - s_n; c_n = c_n > 8 ? 8 : c_n;
    int pos = s_n + (slot < c_n ? slot : 0);
    pos = pos < N_EDGES ? pos : N_EDGES - 1;  // d==0 trailing-node clamp
    int2 pv = pk[pos];

    float accx[8], accy[8], eacc[8];
#pragma unroll
    for (int i = 0; i < 8; ++i) {
        accx[i] = 0.f; accy[i] = 0.f;
        if (EA) eacc[i] = 0.f;
    }

    // ---- wide phase: all 8 nodes' first chunks, one flat load batch ----
#pragma unroll
    for (int i = 0; i < 8; ++i) {
        int di = __shfl(rp, i + 1) - __shfl(rp, i);
        int ci = di > 8 ? 8 : di;
        f16x2 r[8];
#pragma unroll
        for (int u = 0; u < 8; ++u) {
            int s = __shfl(pv.x, i * 8 + u);
            r[u] = *(const f16x2*)&xin[s * HIDDEN + lane * 2];
        }
        float g[4];
        if (EA) {
#pragma unroll
            for (int up = 0; up < 4; ++up) {
                int eid = __shfl(pv.y, i * 8 + 2 * up + half);
                g[up] = ea[eid * EDGE_DIM + k];
            }
        }
#pragma unroll
        for (int u = 0; u < 8; ++u)
            if (u < ci) { accx[i] += (float)r[u].x; accy[i] += (float)r[u].y; }
        if (EA) {
#pragma unroll
            for (int up = 0; up < 4; ++up)
                if (2 * up + half < ci) eacc[i] += g[up];
        }
    }

    // ---- residual: nodes with degree > 8 (wave-uniform loops) ----
#pragma unroll
    for (int i = 0; i < 8; ++i) {
        int si = __shfl(rp, i);
        int ei = __shfl(rp, i + 1);
        int p = si + 8;
        if (p < ei) {
            do {
                int c = ei - p; c = c > 8 ? 8 : c;
                int2 pv2 = pk[p + (slot < c ? slot : 0)];
                f16x2 r[8];
#pragma unroll
                for (int u = 0; u < 8; ++u) {
                    int s = __shfl(pv2.x, u);
                    r[u] = *(const f16x2*)&xin[s * HIDDEN + lane * 2];
                }
                float g[4];
                if (EA) {
#pragma unroll
                    for (int up = 0; up < 4; ++up) {
                        int eid = __shfl(pv2.y, 2 * up + half);
                        g[up] = ea[eid * EDGE_DIM + k];
                    }
                }
#pragma unroll
                for (int u = 0; u < 8; ++u)
                    if (u < c) { accx[i] += (float)r[u].x; accy[i] += (float)r[u].y; }
                if (EA) {
#pragma unroll
                    for (int up = 0; up < 4; ++up)
                        if (2 * up + half < c) eacc[i] += g[up];
                }
                p += c;
            } while (p < ei);
        }
    }

    // ---- write ----
    float dinv[8];
#pragma unroll
    for (int i = 0; i < 8; ++i) {
        int di = __shfl(rp, i + 1) - __shfl(rp, i);
        dinv[i] = 1.f / (float)(di > 1 ? di : 1);
    }
#pragma unroll
    for (int i = 0; i < 8; ++i) {
        f16x2 o;
        o.x = (_Float16)(accx[i] * dinv[i]);
        o.y = (_Float16)(accy[i] * dinv[i]);
        *(f16x2*)&meanb[(n0 + i) * HIDDEN + lane * 2] = o;
    }
    if (EA) {
#pragma unroll
        for (int i = 0; i < 8; ++i) eacc[i] += __shfl_xor(eacc[i], 32);
#pragma unroll
        for (int j = 0; j < 4; ++j) {
            float v  = half ? eacc[4 + j] : eacc[j];
            float dv = half ? dinv[4 + j] : dinv[j];
            int i = half * 4 + j;
            eamb[(n0 + i) * EDGE_DIM + k] = (_Float16)(v * dv);
        }
    }
}

// ===========================================================================
// Node GEMM (layer 1), r2-proven form: full LDS staging of [mean|x|eam],
// out = relu(A @ [Wl;Wr;WeWl] + bias), K=288.
// ===========================================================================
#define APITCH 296  // 288 + 8 f16 pad
__global__ __launch_bounds__(256) void node_gemm_kernel(
        const _Float16* __restrict__ meanb,
        const _Float16* __restrict__ xb,
        const _Float16* __restrict__ eamb,
        const _Float16* __restrict__ Wbs,
        const int* __restrict__ rowptr,
        const float* __restrict__ bl, const float* __restrict__ br,
        const float* __restrict__ beWl,
        _Float16* __restrict__ outb) {
    __shared__ _Float16 s_a[64 * APITCH];  // 37888 B
    __shared__ float s_bias[128];
    __shared__ float s_bw[128];
    __shared__ int s_deg[64];
    int t = threadIdx.x;
    int n0 = blockIdx.x * 64;

    if (t < 128) {
        s_bias[t] = bl[t] + br[t];
        s_bw[t] = beWl[t];
    } else if (t < 192) {
        int m = t - 128;
        int n = n0 + m;
        n = n < N_NODES ? n : N_NODES - 1;
        s_deg[m] = rowptr[n + 1] - rowptr[n];
    }
    for (int i = t; i < 64 * 16; i += 256) {
        int row = i >> 4, seg = i & 15;
        int n = n0 + row;
        n = n < N_NODES ? n : N_NODES - 1;
        *(f16x8*)&s_a[row * APITCH + seg * 8] = *(const f16x8*)&meanb[n * HIDDEN + seg * 8];
        *(f16x8*)&s_a[row * APITCH + 128 + seg * 8] = *(const f16x8*)&xb[n * HIDDEN + seg * 8];
    }
    for (int i = t; i < 64 * 4; i += 256) {
        int row = i >> 2, seg = i & 3;
        int n = n0 + row;
        n = n < N_NODES ? n : N_NODES - 1;
        *(f16x8*)&s_a[row * APITCH + 256 + seg * 8] = *(const f16x8*)&eamb[n * EDGE_DIM + seg * 8];
    }
    __syncthreads();

    int wave = t >> 6;
    int lane = t & 63;
    int col = lane & 15;
    int kgrp = lane >> 4;

    f32x4 acc[8];
#pragma unroll
    for (int nt = 0; nt < 8; ++nt) acc[nt] = (f32x4){0.f, 0.f, 0.f, 0.f};

    const f16x8* __restrict__ Wb = (const f16x8*)Wbs;
#pragma unroll
    for (int ks = 0; ks < 9; ++ks) {
        f16x8 afrag = *(const f16x8*)&s_a[(wave * 16 + col) * APITCH + ks * 32 + kgrp * 8];
#pragma unroll
        for (int nt = 0; nt < 8; ++nt) {
            f16x8 bfrag = Wb[(nt * 9 + ks) * 64 + lane];
            acc[nt] = __builtin_amdgcn_mfma_f32_16x16x32_f16(afrag, bfrag, acc[nt], 0, 0, 0);
        }
    }

#pragma unroll
    for (int nt = 0; nt < 8; ++nt) {
        int feat = nt * 16 + col;
        float b = s_bias[feat];
        float bw = s_bw[feat];
#pragma unroll
        for (int r = 0; r < 4; ++r) {
            int m = wave * 16 + kgrp * 4 + r;
            int n = n0 + m;
            float v = acc[nt][r] + b + (s_deg[m] > 0 ? bw : 0.f);
            v = v > 0.f ? v : 0.f;
            if (n < N_NODES) outb[n * HIDDEN + feat] = (_Float16)v;
        }
    }
}

// ===========================================================================
// Fused layer-2 node GEMM + UV GEMM. Phase A: h2 = relu([mean|h1|eam]@Wbig
// + bias) in registers (never written to global). Transpose h2 tile through
// LDS (aliases the A-tile; LDS stays 39 KB -> 4 blocks/CU). Phase B:
// U[n] = h2[n]@Wp1_top + bp1 ; V[n] = h2[n]@Wp1_bot. Kills the h2b
// round-trip (51.2 MB) and one dispatch.
// ===========================================================================
#define UPITCH 136  // 128 + 8 f16 pad
__global__ __launch_bounds__(256) void node_gemm_uv_kernel(
        const _Float16* __restrict__ meanb,
        const _Float16* __restrict__ h1,
        const _Float16* __restrict__ eamb,
        const _Float16* __restrict__ Wbs,
        const int* __restrict__ rowptr,
        const float* __restrict__ bl, const float* __restrict__ br,
        const float* __restrict__ beWl,
        const _Float16* __restrict__ Wuv,
        const float* __restrict__ bp1,
        _Float16* __restrict__ U,
        _Float16* __restrict__ V) {
    __shared__ _Float16 s_a[64 * APITCH];  // 37888 B (phase B aliases first 17408 B)
    __shared__ float s_bias[128];
    __shared__ float s_bw[128];
    __shared__ int s_deg[64];
    int t = threadIdx.x;
    int n0 = blockIdx.x * 64;

    if (t < 128) {
        s_bias[t] = bl[t] + br[t];
        s_bw[t] = beWl[t];
    } else if (t < 192) {
        int m = t - 128;
        int n = n0 + m;
        n = n < N_NODES ? n : N_NODES - 1;
        s_deg[m] = rowptr[n + 1] - rowptr[n];
    }
    for (int i = t; i < 64 * 16; i += 256) {
        int row = i >> 4, seg = i & 15;
        int n = n0 + row;
        n = n < N_NODES ? n : N_NODES - 1;
        *(f16x8*)&s_a[row * APITCH + seg * 8] = *(const f16x8*)&meanb[n * HIDDEN + seg * 8];
        *(f16x8*)&s_a[row * APITCH + 128 + seg * 8] = *(const f16x8*)&h1[n * HIDDEN + seg * 8];
    }
    for (int i = t; i < 64 * 4; i += 256) {
        int row = i >> 2, seg = i & 3;
        int n = n0 + row;
        n = n < N_NODES ? n : N_NODES - 1;
        *(f16x8*)&s_a[row * APITCH + 256 + seg * 8] = *(const f16x8*)&eamb[n * EDGE_DIM + seg * 8];
    }
    __syncthreads();

    int wave = t >> 6;
    int lane = t & 63;
    int col = lane & 15;
    int kgrp = lane >> 4;

    // ---- phase A: K=288 GEMM ----
    f32x4 acc[8];
#pragma unroll
    for (int nt = 0; nt < 8; ++nt) acc[nt] = (f32x4){0.f, 0.f, 0.f, 0.f};

    const f16x8* __restrict__ Wb = (const f16x8*)Wbs;
#pragma unroll
    for (int ks = 0; ks < 9; ++ks) {
        f16x8 afrag = *(const f16x8*)&s_a[(wave * 16 + col) * APITCH + ks * 32 + kgrp * 8];
#pragma unroll
        for (int nt = 0; nt < 8; ++nt) {
            f16x8 bfrag = Wb[(nt * 9 + ks) * 64 + lane];
            acc[nt] = __builtin_amdgcn_mfma_f32_16x16x32_f16(afrag, bfrag, acc[nt], 0, 0, 0);
        }
    }

    // epilogue in registers: h2 = relu(acc + bias) as f16
    f16x4 h2v[8];
#pragma unroll
    for (int nt = 0; nt < 8; ++nt) {
        int feat = nt * 16 + col;
        float b = s_bias[feat];
        float bw = s_bw[feat];
#pragma unroll
        for (int r = 0; r < 4; ++r) {
            int m = wave * 16 + kgrp * 4 + r;
            float v = acc[nt][r] + b + (s_deg[m] > 0 ? bw : 0.f);
            v = v > 0.f ? v : 0.f;
            h2v[nt][r] = (_Float16)v;
        }
    }

    // ---- transpose h2 tile through LDS (aliases s_a) ----
    __syncthreads();  // all phase-A reads of s_a done
    _Float16* s_h = s_a;
#pragma unroll
    for (int nt = 0; nt < 8; ++nt) {
        int feat = nt * 16 + col;
#pragma unroll
        for (int r = 0; r < 4; ++r) {
            int m = wave * 16 + kgrp * 4 + r;
            s_h[m * UPITCH + feat] = h2v[nt][r];
        }
    }
    if (t < 128) s_bias[t] = bp1[t];  // re-purpose for phase-B bias
    __syncthreads();

    // ---- phase B: UV GEMM, K=128, N=256 ----
    f32x4 acc2[16];
#pragma unroll
    for (int nt = 0; nt < 16; ++nt) acc2[nt] = (f32x4){0.f, 0.f, 0.f, 0.f};

    const f16x8* __restrict__ Wb2 = (const f16x8*)Wuv;
#pragma unroll
    for (int ks = 0; ks < 4; ++ks) {
        f16x8 afrag = *(const f16x8*)&s_h[(wave * 16 + col) * UPITCH + ks * 32 + kgrp * 8];
#pragma unroll
        for (int nt = 0; nt < 16; ++nt) {
            f16x8 bfrag = Wb2[(nt * 4 + ks) * 64 + lane];
            acc2[nt] = __builtin_amdgcn_mfma_f32_16x16x32_f16(afrag, bfrag, acc2[nt], 0, 0, 0);
        }
    }

#pragma unroll
    for (int nt = 0; nt < 16; ++nt) {
        int feat = nt * 16 + col;
        float b = (nt < 8) ? s_bias[feat] : 0.f;  // bp1 folded into U only
#pragma unroll
        for (int r = 0; r < 4; ++r) {
            int m = wave * 16 + kgrp * 4 + r;
            int n = n0 + m;
            if (n < N_NODES) {
                _Float16 o = (_Float16)(acc2[nt][r] + b);
                if (nt < 8) U[n * 128 + feat] = o;
                else        V[n * 128 + (feat - 128)] = o;
            }
        }
    }
}

// ===========================================================================
// Wp1 -> UV-GEMM B fragments: K=128 (h dims), N=256 (U cols | V cols).
// ===========================================================================
__global__ void wp1uv_swizzle_kernel(const float* __restrict__ Wp1,
                                     _Float16* __restrict__ Wuv) {
    int idx = blockIdx.x * 256 + threadIdx.x;  // 32768
    if (idx >= 32768) return;
    int j = idx & 7;
    int lane = (idx >> 3) & 63;
    int ks = (idx >> 9) & 3;
    int nt = (idx >> 11) & 15;
    int k = ks * 32 + ((lane >> 4) & 3) * 8 + j;
    int n = nt * 16 + (lane & 15);
    float v = (n < 128) ? Wp1[k * 128 + n] : Wp1[(128 + k) * 128 + (n - 128)];
    Wuv[idx] = (_Float16)v;
}

// ===========================================================================
// Edge predictor, LDS-free, CSR(dst-sorted) order (r2-proven shuffle form):
// out[eid] = relu(U[src] + V[dst]) @ Wp2 + bp2.
// Wave = 2 edge slots x 32 lanes x 4 feats; 4-deep unroll -> 8 edges/wave.
// N_EDGES = 32 * 18750 exactly.
// ===========================================================================
__global__ __launch_bounds__(256) void edge_pred_kernel(
        const _Float16* __restrict__ U,
        const _Float16* __restrict__ V,
        const int2* __restrict__ pk,
        const int* __restrict__ pdst,
        const float* __restrict__ Wp2,
        const float* __restrict__ bp2,
        float* __restrict__ out) {
    int t = threadIdx.x;
    int wave = t >> 6;
    int lane = t & 63;
    int slot = lane >> 5;
    int k4 = (lane & 31) * 4;

    float4 wa = *(const float4*)&Wp2[k4 * 2];
    float4 wb = *(const float4*)&Wp2[k4 * 2 + 4];
    float b0 = bp2[0], b1 = bp2[1];

    int e0 = blockIdx.x * 32 + wave * 8;

    int2 pv[4];
    int dn[4];
#pragma unroll
    for (int u = 0; u < 4; ++u) {
        int pos = e0 + 2 * u + slot;
        pv[u] = pk[pos];
        dn[u] = pdst[pos];
    }
    f16x4 uu[4], vv[4];
#pragma unroll
    for (int u = 0; u < 4; ++u) {
        uu[u] = *(const f16x4*)&U[pv[u].x * 128 + k4];
        vv[u] = *(const f16x4*)&V[dn[u] * 128 + k4];
    }

    float p0[4], p1[4];
#pragma unroll
    for (int u = 0; u < 4; ++u) {
        float z0 = (float)uu[u].x + (float)vv[u].x; z0 = z0 > 0.f ? z0 : 0.f;
        float z1 = (float)uu[u].y + (float)vv[u].y; z1 = z1 > 0.f ? z1 : 0.f;
        float z2 = (float)uu[u].z + (float)vv[u].z; z2 = z2 > 0.f ? z2 : 0.f;
        float z3 = (float)uu[u].w + (float)vv[u].w; z3 = z3 > 0.f ? z3 : 0.f;
        p0[u] = z0 * wa.x + z1 * wa.z + z2 * wb.x + z3 * wb.z;
        p1[u] = z0 * wa.y + z1 * wa.w + z2 * wb.y + z3 * wb.w;
    }
#pragma unroll
    for (int m = 1; m < 32; m <<= 1) {
#pragma unroll
        for (int u = 0; u < 4; ++u) {
            p0[u] += __shfl_xor(p0[u], m);
            p1[u] += __shfl_xor(p1[u], m);
        }
    }
    if ((lane & 31) == 0) {
#pragma unroll
        for (int u = 0; u < 4; ++u) {
            float2 o;
            o.x = p0[u] + b0;
            o.y = p1[u] + b1;
            *(float2*)&out[pv[u].y * 2] = o;
        }
    }
}

// ===========================================================================
extern "C" void kernel_launch(void* const* d_in, const int* in_sizes, int n_in,
                              void* d_out, int out_size, void* d_ws, size_t ws_size,
                              hipStream_t stream) {
    const float* x   = (const float*)d_in[0];
    const int*   ei  = (const int*)d_in[1];
    const float* ea  = (const float*)d_in[2];
    const float* We1 = (const float*)d_in[3];
    const float* be1 = (const float*)d_in[4];
    const float* Wl1 = (const float*)d_in[5];
    const float* bl1 = (const float*)d_in[6];
    const float* Wr1 = (const float*)d_in[7];
    const float* br1 = (const float*)d_in[8];
    const float* We2 = (const float*)d_in[9];
    const float* be2 = (const float*)d_in[10];
    const float* Wl2 = (const float*)d_in[11];
    const float* bl2 = (const float*)d_in[12];
    const float* Wr2 = (const float*)d_in[13];
    const float* br2 = (const float*)d_in[14];
    const float* Wp1 = (const float*)d_in[15];
    const float* bp1 = (const float*)d_in[16];
    const float* Wp2 = (const float*)d_in[17];
    const float* bp2 = (const float*)d_in[18];
    float* out = (float*)d_out;

    const int* src = ei;
    const int* dst = ei + N_EDGES;

    char* ws = (char*)d_ws;
    int*   cnt     = (int*)(ws + 0);           // 409600
    int*   scanout = (int*)(ws + 409600);      // 409600
    int*   bsum    = (int*)(ws + 819200);      // 8192
    int*   rowptr  = (int*)(ws + 827392);      // 409600 (N+1 ints)
    int*   cur     = (int*)(ws + 1236992);     // 409600
    int2*  pk      = (int2*)(ws + 1646592);    // 4800512
    float* WeWl1   = (float*)(ws + 6447104);   // 16384
    float* beWl1   = (float*)(ws + 6463488);   // 512
    float* WeWl2   = (float*)(ws + 6464000);   // 16384
    float* beWl2   = (float*)(ws + 6480384);   // 512
    _Float16* eamb = (_Float16*)(ws + 6480896);   // 6.4 MB
    _Float16* xb   = (_Float16*)(ws + 12880896);  // 25.6 MB
    _Float16* meanb= (_Float16*)(ws + 38480896);  // 25.6 MB
    _Float16* h1b  = (_Float16*)(ws + 64080896);  // 25.6 MB
    // U aliases xb (dead after node_gemm layer 1); V reuses old h2b region
    _Float16* U    = (_Float16*)(ws + 12880896);  // 25.6 MB
    _Float16* V    = (_Float16*)(ws + 89680896);  // 25.6 MB
    _Float16* Wbs1 = (_Float16*)(ws + 115280896); // 73728
    _Float16* Wbs2 = (_Float16*)(ws + 115354624); // 73728
    _Float16* Wuv  = (_Float16*)(ws + 115428352); // 65536
    int*   pdst    = (int*)(ws + 115493888);      // 2.4 MB

    const int EB = (N_EDGES + 255) / 256;

    // ---- CSR build ----
    hipMemsetAsync(cnt, 0, N_NODES * sizeof(int), stream);
    hist_kernel<<<EB, 256, 0, stream>>>(dst, cnt);
    scan1_kernel<<<NBLK, 256, 0, stream>>>(cnt, scanout, bsum);
    scan2_kernel<<<1, 512, 0, stream>>>(bsum);
    scan3_kernel<<<NBLK, 256, 0, stream>>>(cnt, scanout, bsum, rowptr, cur);
    fill_kernel<<<EB, 256, 0, stream>>>(src, dst, cur, pk, pdst);

    // ---- graph-invariant precompute (batched) ----
    wewl2_kernel<<<33, 256, 0, stream>>>(We1, be1, Wl1, We2, be2, Wl2,
                                         WeWl1, beWl1, WeWl2, beWl2);
    xb_kernel<<<(N_NODES * HIDDEN / 2 + 255) / 256, 256, 0, stream>>>(x, xb);
    wbig2_kernel<<<288, 256, 0, stream>>>(Wl1, Wr1, WeWl1, Wbs1,
                                          Wl2, Wr2, WeWl2, Wbs2);
    wp1uv_swizzle_kernel<<<128, 256, 0, stream>>>(Wp1, Wuv);

    // ---- layer 1 ----
    agg_kernel_t<true><<<N_NODES / 32, 256, 0, stream>>>(xb, rowptr, pk, ea, meanb, eamb);
    node_gemm_kernel<<<(N_NODES + 63) / 64, 256, 0, stream>>>(
        meanb, xb, eamb, Wbs1, rowptr, bl1, br1, beWl1, h1b);

    // ---- layer 2 + UV fused (h2 never hits HBM) ----
    agg_kernel_t<false><<<N_NODES / 32, 256, 0, stream>>>(h1b, rowptr, pk, nullptr, meanb, nullptr);
    node_gemm_uv_kernel<<<(N_NODES + 63) / 64, 256, 0, stream>>>(
        meanb, h1b, eamb, Wbs2, rowptr, bl2, br2, beWl2, Wuv, bp1, U, V);

    // ---- edge predictor ----
    edge_pred_kernel<<<N_EDGES / 32, 256, 0, stream>>>(U, V, pk, pdst, Wp2, bp2, out);
}

// Round 7
// 452.021 us; speedup vs baseline: 1.1417x; 1.1417x over previous
//
#include <hip/hip_runtime.h>

#define N_NODES 100000
#define N_EDGES 600000
#define IN_DIM 128
#define EDGE_DIM 32
#define HIDDEN 128
#define NUM_CLASSES 2
#define NBLK 391  // ceil(N_NODES/256)

typedef __attribute__((ext_vector_type(4))) float f32x4;
typedef _Float16 f16x2 __attribute__((ext_vector_type(2)));
typedef _Float16 f16x4 __attribute__((ext_vector_type(4)));
typedef _Float16 f16x8 __attribute__((ext_vector_type(8)));

// ===========================================================================
// CSR build
// ===========================================================================
__global__ void hist_kernel(const int* __restrict__ dst, int* __restrict__ cnt) {
    int e = blockIdx.x * blockDim.x + threadIdx.x;
    if (e < N_EDGES) atomicAdd(&cnt[dst[e]], 1);
}

__global__ void scan1_kernel(const int* __restrict__ cnt,
                             int* __restrict__ scanout, int* __restrict__ bsum) {
    __shared__ int s[256];
    int tid = threadIdx.x;
    int i = blockIdx.x * 256 + tid;
    int v = (i < N_NODES) ? cnt[i] : 0;
    s[tid] = v;
    __syncthreads();
#pragma unroll
    for (int off = 1; off < 256; off <<= 1) {
        int t = 0;
        if (tid >= off) t = s[tid - off];
        __syncthreads();
        if (tid >= off) s[tid] += t;
        __syncthreads();
    }
    if (i < N_NODES) scanout[i] = s[tid];
    if (tid == 255) bsum[blockIdx.x] = s[255];
}

__global__ void scan2_kernel(int* __restrict__ bsum) {
    __shared__ int s[512];
    int tid = threadIdx.x;
    int v = (tid < NBLK) ? bsum[tid] : 0;
    s[tid] = v;
    __syncthreads();
#pragma unroll
    for (int off = 1; off < 512; off <<= 1) {
        int t = 0;
        if (tid >= off) t = s[tid - off];
        __syncthreads();
        if (tid >= off) s[tid] += t;
        __syncthreads();
    }
    if (tid < NBLK) bsum[tid] = s[tid] - v;  // exclusive
}

__global__ void scan3_kernel(const int* __restrict__ cnt,
                             const int* __restrict__ scanout,
                             const int* __restrict__ bsum,
                             int* __restrict__ rowptr, int* __restrict__ cur) {
    int i = blockIdx.x * 256 + threadIdx.x;
    if (i < N_NODES) {
        int excl = scanout[i] + bsum[i >> 8] - cnt[i];
        rowptr[i] = excl;
        cur[i] = excl;
    }
    if (i == 0) rowptr[N_NODES] = N_EDGES;
}

// pk[pos] = { src, edge id } ; pdst[pos] = dst
__global__ void fill_kernel(const int* __restrict__ src, const int* __restrict__ dst,
                            int* __restrict__ cur, int2* __restrict__ pk,
                            int* __restrict__ pdst) {
    int e = blockIdx.x * blockDim.x + threadIdx.x;
    if (e < N_EDGES) {
        int d = dst[e];
        int pos = atomicAdd(&cur[d], 1);
        int2 v;
        v.x = src[e];
        v.y = e;
        pk[pos] = v;
        pdst[pos] = d;
    }
}

// ===========================================================================
// x -> fp16 copy
// ===========================================================================
__global__ void xb_kernel(const float* __restrict__ x, _Float16* __restrict__ xb) {
    int i = blockIdx.x * 256 + threadIdx.x;  // over N*H/2 float2
    if (i < N_NODES * HIDDEN / 2) {
        float2 v = ((const float2*)x)[i];
        f16x2 o;
        o.x = (_Float16)v.x;
        o.y = (_Float16)v.y;
        *(f16x2*)&xb[i * 2] = o;
    }
}

// ===========================================================================
// Both layers batched: WeWl = We @ Wl (32x128), beWl = be @ Wl (128)
// ===========================================================================
__global__ void wewl2_kernel(const float* __restrict__ We1, const float* __restrict__ be1,
                             const float* __restrict__ Wl1,
                             const float* __restrict__ We2, const float* __restrict__ be2,
                             const float* __restrict__ Wl2,
                             float* __restrict__ WeWl1, float* __restrict__ beWl1,
                             float* __restrict__ WeWl2, float* __restrict__ beWl2) {
    int idx0 = blockIdx.x * 256 + threadIdx.x;
    if (idx0 >= 2 * 33 * 128) return;
    int layer = idx0 >= 33 * 128;
    int idx = idx0 - layer * 33 * 128;
    const float* We = layer ? We2 : We1;
    const float* be = layer ? be2 : be1;
    const float* Wl = layer ? Wl2 : Wl1;
    float* WeWl = layer ? WeWl2 : WeWl1;
    float* beWl = layer ? beWl2 : beWl1;
    int r = idx >> 7;
    int n = idx & 127;
    float s = 0.f;
    if (r < 32) {
        for (int j = 0; j < 128; ++j) s += We[r * 128 + j] * Wl[j * 128 + n];
        WeWl[r * 128 + n] = s;
    } else {
        for (int j = 0; j < 128; ++j) s += be[j] * Wl[j * 128 + n];
        beWl[n] = s;
    }
}

// ===========================================================================
// Both layers batched: Wbig = [Wl;Wr;WeWl] -> fp16 MFMA B-frag order, K=288.
// ===========================================================================
__global__ void wbig2_kernel(const float* __restrict__ Wl1, const float* __restrict__ Wr1,
                             const float* __restrict__ WeWl1, _Float16* __restrict__ Wbs1,
                             const float* __restrict__ Wl2, const float* __restrict__ Wr2,
                             const float* __restrict__ WeWl2, _Float16* __restrict__ Wbs2) {
    int idx0 = blockIdx.x * 256 + threadIdx.x;
    if (idx0 >= 2 * 36864) return;
    int layer = idx0 >= 36864;
    int idx = idx0 - layer * 36864;
    const float* Wl = layer ? Wl2 : Wl1;
    const float* Wr = layer ? Wr2 : Wr1;
    const float* WeWl = layer ? WeWl2 : WeWl1;
    _Float16* Wbs = layer ? Wbs2 : Wbs1;
    int j = idx & 7;
    int lane = (idx >> 3) & 63;
    int rem = idx >> 9;  // 0..71
    int ks = rem % 9;
    int nt = rem / 9;
    int k = ks * 32 + ((lane >> 4) & 3) * 8 + j;
    int n = nt * 16 + (lane & 15);
    float v = (k < 128) ? Wl[k * 128 + n]
            : (k < 256) ? Wr[(k - 128) * 128 + n]
                        : WeWl[(k - 256) * 128 + n];
    Wbs[idx] = (_Float16)v;
}

// ===========================================================================
// Per-wave VGPR aggregation, wide-issue (r2-proven; VGPR~60, 8 waves/SIMD).
// Do NOT fuse with MFMA GEMM (r4: occupancy 35%->18%, regressed).
// ===========================================================================
template <bool EA>
__global__ __launch_bounds__(256) void agg_kernel_t(const _Float16* __restrict__ xin,
                                                    const int* __restrict__ rowptr,
                                                    const int2* __restrict__ pk,
                                                    const float* __restrict__ ea,
                                                    _Float16* __restrict__ meanb,
                                                    _Float16* __restrict__ eamb) {
    int wid = blockIdx.x * 4 + (threadIdx.x >> 6);
    int lane = threadIdx.x & 63;
    int node = lane >> 3;
    int slot = lane & 7;
    int half = lane >> 5;   // EA path
    int k = lane & 31;      // EA path
    int n0 = wid * 8;       // N_NODES % 8 == 0, no tail guard needed

    int rp = rowptr[n0 + (lane < 9 ? lane : 8)];
    int s_n = __shfl(rp, node);
    int e_n = __shfl(rp, node + 1);
    int c_n = e_n - s_n; c_n = c_n > 8 ? 8 : c_n;
    int pos = s_n + (slot < c_n ? slot : 0);
    pos = pos < N_EDGES ? pos : N_EDGES - 1;  // d==0 trailing-node clamp
    int2 pv = pk[pos];

    float accx[8], accy[8], eacc[8];
#pragma unroll
    for (int i = 0; i < 8; ++i) {
        accx[i] = 0.f; accy[i] = 0.f;
        if (EA) eacc[i] = 0.f;
    }

    // ---- wide phase: all 8 nodes' first chunks, one flat load batch ----
#pragma unroll
    for (int i = 0; i < 8; ++i) {
        int di = __shfl(rp, i + 1) - __shfl(rp, i);
        int ci = di > 8 ? 8 : di;
        f16x2 r[8];
#pragma unroll
        for (int u = 0; u < 8; ++u) {
            int s = __shfl(pv.x, i * 8 + u);
            r[u] = *(const f16x2*)&xin[s * HIDDEN + lane * 2];
        }
        float g[4];
        if (EA) {
#pragma unroll
            for (int up = 0; up < 4; ++up) {
                int eid = __shfl(pv.y, i * 8 + 2 * up + half);
                g[up] = ea[eid * EDGE_DIM + k];
            }
        }
#pragma unroll
        for (int u = 0; u < 8; ++u)
            if (u < ci) { accx[i] += (float)r[u].x; accy[i] += (float)r[u].y; }
        if (EA) {
#pragma unroll
            for (int up = 0; up < 4; ++up)
                if (2 * up + half < ci) eacc[i] += g[up];
        }
    }

    // ---- residual: nodes with degree > 8 (wave-uniform loops) ----
#pragma unroll
    for (int i = 0; i < 8; ++i) {
        int si = __shfl(rp, i);
        int ei = __shfl(rp, i + 1);
        int p = si + 8;
        if (p < ei) {
            do {
                int c = ei - p; c = c > 8 ? 8 : c;
                int2 pv2 = pk[p + (slot < c ? slot : 0)];
                f16x2 r[8];
#pragma unroll
                for (int u = 0; u < 8; ++u) {
                    int s = __shfl(pv2.x, u);
                    r[u] = *(const f16x2*)&xin[s * HIDDEN + lane * 2];
                }
                float g[4];
                if (EA) {
#pragma unroll
                    for (int up = 0; up < 4; ++up) {
                        int eid = __shfl(pv2.y, 2 * up + half);
                        g[up] = ea[eid * EDGE_DIM + k];
                    }
                }
#pragma unroll
                for (int u = 0; u < 8; ++u)
                    if (u < c) { accx[i] += (float)r[u].x; accy[i] += (float)r[u].y; }
                if (EA) {
#pragma unroll
                    for (int up = 0; up < 4; ++up)
                        if (2 * up + half < c) eacc[i] += g[up];
                }
                p += c;
            } while (p < ei);
        }
    }

    // ---- write ----
    float dinv[8];
#pragma unroll
    for (int i = 0; i < 8; ++i) {
        int di = __shfl(rp, i + 1) - __shfl(rp, i);
        dinv[i] = 1.f / (float)(di > 1 ? di : 1);
    }
#pragma unroll
    for (int i = 0; i < 8; ++i) {
        f16x2 o;
        o.x = (_Float16)(accx[i] * dinv[i]);
        o.y = (_Float16)(accy[i] * dinv[i]);
        *(f16x2*)&meanb[(n0 + i) * HIDDEN + lane * 2] = o;
    }
    if (EA) {
#pragma unroll
        for (int i = 0; i < 8; ++i) eacc[i] += __shfl_xor(eacc[i], 32);
#pragma unroll
        for (int j = 0; j < 4; ++j) {
            float v  = half ? eacc[4 + j] : eacc[j];
            float dv = half ? dinv[4 + j] : dinv[j];
            int i = half * 4 + j;
            eamb[(n0 + i) * EDGE_DIM + k] = (_Float16)(v * dv);
        }
    }
}

// ===========================================================================
// Node GEMM via f16 MFMA: out = relu([mean|x|eam] @ [Wl;Wr;WeWl] + bias), K=288.
// nt-SPLIT loop nesting: wave w owns n-tiles {2w, 2w+1} across ALL 64 rows.
// Per ks: 2 B-frag global loads reused over 4 row-tiles of LDS A-frags.
// B-frag traffic per wave: 18 KB (was 72 KB) — 4x less L2/latency exposure.
// ===========================================================================
#define APITCH 296  // 288 + 8 f16 pad
__global__ __launch_bounds__(256) void node_gemm_kernel(
        const _Float16* __restrict__ meanb,
        const _Float16* __restrict__ xb,
        const _Float16* __restrict__ eamb,
        const _Float16* __restrict__ Wbs,
        const int* __restrict__ rowptr,
        const float* __restrict__ bl, const float* __restrict__ br,
        const float* __restrict__ beWl,
        _Float16* __restrict__ outb) {
    __shared__ _Float16 s_a[64 * APITCH];  // 37888 B
    __shared__ float s_bias[128];
    __shared__ float s_bw[128];
    __shared__ int s_deg[64];
    int t = threadIdx.x;
    int n0 = blockIdx.x * 64;

    if (t < 128) {
        s_bias[t] = bl[t] + br[t];
        s_bw[t] = beWl[t];
    } else if (t < 192) {
        int m = t - 128;
        int n = n0 + m;
        n = n < N_NODES ? n : N_NODES - 1;
        s_deg[m] = rowptr[n + 1] - rowptr[n];
    }
    for (int i = t; i < 64 * 16; i += 256) {
        int row = i >> 4, seg = i & 15;
        int n = n0 + row;
        n = n < N_NODES ? n : N_NODES - 1;
        *(f16x8*)&s_a[row * APITCH + seg * 8] = *(const f16x8*)&meanb[n * HIDDEN + seg * 8];
        *(f16x8*)&s_a[row * APITCH + 128 + seg * 8] = *(const f16x8*)&xb[n * HIDDEN + seg * 8];
    }
    for (int i = t; i < 64 * 4; i += 256) {
        int row = i >> 2, seg = i & 3;
        int n = n0 + row;
        n = n < N_NODES ? n : N_NODES - 1;
        *(f16x8*)&s_a[row * APITCH + 256 + seg * 8] = *(const f16x8*)&eamb[n * EDGE_DIM + seg * 8];
    }
    __syncthreads();

    int wave = t >> 6;
    int lane = t & 63;
    int col = lane & 15;
    int kgrp = lane >> 4;

    f32x4 acc[4][2];  // [row-tile][n-tile within wave's pair]
#pragma unroll
    for (int rt = 0; rt < 4; ++rt) {
        acc[rt][0] = (f32x4){0.f, 0.f, 0.f, 0.f};
        acc[rt][1] = (f32x4){0.f, 0.f, 0.f, 0.f};
    }

    const f16x8* __restrict__ Wb = (const f16x8*)Wbs;
#pragma unroll
    for (int ks = 0; ks < 9; ++ks) {
        f16x8 b0 = Wb[((2 * wave + 0) * 9 + ks) * 64 + lane];
        f16x8 b1 = Wb[((2 * wave + 1) * 9 + ks) * 64 + lane];
#pragma unroll
        for (int rt = 0; rt < 4; ++rt) {
            f16x8 afrag = *(const f16x8*)&s_a[(rt * 16 + col) * APITCH + ks * 32 + kgrp * 8];
            acc[rt][0] = __builtin_amdgcn_mfma_f32_16x16x32_f16(afrag, b0, acc[rt][0], 0, 0, 0);
            acc[rt][1] = __builtin_amdgcn_mfma_f32_16x16x32_f16(afrag, b1, acc[rt][1], 0, 0, 0);
        }
    }

#pragma unroll
    for (int rt = 0; rt < 4; ++rt) {
#pragma unroll
        for (int j = 0; j < 2; ++j) {
            int feat = (2 * wave + j) * 16 + col;
            float b = s_bias[feat];
            float bw = s_bw[feat];
#pragma unroll
            for (int r = 0; r < 4; ++r) {
                int m = rt * 16 + kgrp * 4 + r;
                int n = n0 + m;
                float v = acc[rt][j][r] + b + (s_deg[m] > 0 ? bw : 0.f);
                v = v > 0.f ? v : 0.f;
                if (n < N_NODES) outb[n * HIDDEN + feat] = (_Float16)v;
            }
        }
    }
}

// ===========================================================================
// Wp1 -> UV-GEMM B fragments: K=128 (h dims), N=256 (U cols | V cols).
// ===========================================================================
__global__ void wp1uv_swizzle_kernel(const float* __restrict__ Wp1,
                                     _Float16* __restrict__ Wuv) {
    int idx = blockIdx.x * 256 + threadIdx.x;  // 32768
    if (idx >= 32768) return;
    int j = idx & 7;
    int lane = (idx >> 3) & 63;
    int ks = (idx >> 9) & 3;
    int nt = (idx >> 11) & 15;
    int k = ks * 32 + ((lane >> 4) & 3) * 8 + j;
    int n = nt * 16 + (lane & 15);
    float v = (n < 128) ? Wp1[k * 128 + n] : Wp1[(128 + k) * 128 + (n - 128)];
    Wuv[idx] = (_Float16)v;
}

// ===========================================================================
// UV GEMM: UV[n][0:128] = h[n]@Wp1_top + bp1 ; UV[n][128:256] = h[n]@Wp1_bot.
// nt-SPLIT: wave w owns n-tiles {4w..4w+3} across ALL 64 rows; per ks,
// 4 B-frag loads reused over 4 row-tiles (B traffic 4x less than r2 form).
// ===========================================================================
#define UPITCH 136  // 128 + 8 f16 pad
__global__ __launch_bounds__(256) void uv_gemm_kernel(
        const _Float16* __restrict__ h,
        const _Float16* __restrict__ Wuv,
        const float* __restrict__ bp1,
        _Float16* __restrict__ UV) {
    __shared__ _Float16 s_a[64 * UPITCH];  // 17408 B
    __shared__ float s_bias[256];
    int t = threadIdx.x;
    int n0 = blockIdx.x * 64;

    s_bias[t] = (t < 128) ? bp1[t] : 0.f;
    for (int i = t; i < 64 * 16; i += 256) {
        int row = i >> 4, seg = i & 15;
        int n = n0 + row;
        n = n < N_NODES ? n : N_NODES - 1;
        *(f16x8*)&s_a[row * UPITCH + seg * 8] = *(const f16x8*)&h[n * HIDDEN + seg * 8];
    }
    __syncthreads();

    int wave = t >> 6;
    int lane = t & 63;
    int col = lane & 15;
    int kgrp = lane >> 4;

    f32x4 acc[4][4];  // [row-tile][n-tile within wave's quad]
#pragma unroll
    for (int rt = 0; rt < 4; ++rt)
#pragma unroll
        for (int j = 0; j < 4; ++j) acc[rt][j] = (f32x4){0.f, 0.f, 0.f, 0.f};

    const f16x8* __restrict__ Wb = (const f16x8*)Wuv;
#pragma unroll
    for (int ks = 0; ks < 4; ++ks) {
        f16x8 bf[4];
#pragma unroll
        for (int j = 0; j < 4; ++j)
            bf[j] = Wb[((4 * wave + j) * 4 + ks) * 64 + lane];
#pragma unroll
        for (int rt = 0; rt < 4; ++rt) {
            f16x8 afrag = *(const f16x8*)&s_a[(rt * 16 + col) * UPITCH + ks * 32 + kgrp * 8];
#pragma unroll
            for (int j = 0; j < 4; ++j)
                acc[rt][j] = __builtin_amdgcn_mfma_f32_16x16x32_f16(afrag, bf[j], acc[rt][j], 0, 0, 0);
        }
    }

#pragma unroll
    for (int rt = 0; rt < 4; ++rt) {
#pragma unroll
        for (int j = 0; j < 4; ++j) {
            int feat = (4 * wave + j) * 16 + col;
            float b = s_bias[feat];
#pragma unroll
            for (int r = 0; r < 4; ++r) {
                int m = rt * 16 + kgrp * 4 + r;
                int n = n0 + m;
                if (n < N_NODES) UV[n * 256 + feat] = (_Float16)(acc[rt][j][r] + b);
            }
        }
    }
}

// ===========================================================================
// Edge predictor, LDS-free, CSR(dst-sorted) order (r2-proven shuffle form):
// out[eid] = relu(U[src] + V[dst]) @ Wp2 + bp2.
// Wave = 2 edge slots x 32 lanes x 4 feats; 4-deep unroll -> 8 edges/wave.
// N_EDGES = 32 * 18750 exactly.
// ===========================================================================
__global__ __launch_bounds__(256) void edge_pred_kernel(
        const _Float16* __restrict__ UV,
        const int2* __restrict__ pk,
        const int* __restrict__ pdst,
        const float* __restrict__ Wp2,
        const float* __restrict__ bp2,
        float* __restrict__ out) {
    int t = threadIdx.x;
    int wave = t >> 6;
    int lane = t & 63;
    int slot = lane >> 5;
    int k4 = (lane & 31) * 4;

    float4 wa = *(const float4*)&Wp2[k4 * 2];
    float4 wb = *(const float4*)&Wp2[k4 * 2 + 4];
    float b0 = bp2[0], b1 = bp2[1];

    int e0 = blockIdx.x * 32 + wave * 8;

    int2 pv[4];
    int dn[4];
#pragma unroll
    for (int u = 0; u < 4; ++u) {
        int pos = e0 + 2 * u + slot;
        pv[u] = pk[pos];
        dn[u] = pdst[pos];
    }
    f16x4 uu[4], vv[4];
#pragma unroll
    for (int u = 0; u < 4; ++u) {
        uu[u] = *(const f16x4*)&UV[pv[u].x * 256 + k4];
        vv[u] = *(const f16x4*)&UV[dn[u] * 256 + 128 + k4];
    }

    float p0[4], p1[4];
#pragma unroll
    for (int u = 0; u < 4; ++u) {
        float z0 = (float)uu[u].x + (float)vv[u].x; z0 = z0 > 0.f ? z0 : 0.f;
        float z1 = (float)uu[u].y + (float)vv[u].y; z1 = z1 > 0.f ? z1 : 0.f;
        float z2 = (float)uu[u].z + (float)vv[u].z; z2 = z2 > 0.f ? z2 : 0.f;
        float z3 = (float)uu[u].w + (float)vv[u].w; z3 = z3 > 0.f ? z3 : 0.f;
        p0[u] = z0 * wa.x + z1 * wa.z + z2 * wb.x + z3 * wb.z;
        p1[u] = z0 * wa.y + z1 * wa.w + z2 * wb.y + z3 * wb.w;
    }
#pragma unroll
    for (int m = 1; m < 32; m <<= 1) {
#pragma unroll
        for (int u = 0; u < 4; ++u) {
            p0[u] += __shfl_xor(p0[u], m);
            p1[u] += __shfl_xor(p1[u], m);
        }
    }
    if ((lane & 31) == 0) {
#pragma unroll
        for (int u = 0; u < 4; ++u) {
            float2 o;
            o.x = p0[u] + b0;
            o.y = p1[u] + b1;
            *(float2*)&out[pv[u].y * 2] = o;
        }
    }
}

// ===========================================================================
extern "C" void kernel_launch(void* const* d_in, const int* in_sizes, int n_in,
                              void* d_out, int out_size, void* d_ws, size_t ws_size,
                              hipStream_t stream) {
    const float* x   = (const float*)d_in[0];
    const int*   ei  = (const int*)d_in[1];
    const float* ea  = (const float*)d_in[2];
    const float* We1 = (const float*)d_in[3];
    const float* be1 = (const float*)d_in[4];
    const float* Wl1 = (const float*)d_in[5];
    const float* bl1 = (const float*)d_in[6];
    const float* Wr1 = (const float*)d_in[7];
    const float* br1 = (const float*)d_in[8];
    const float* We2 = (const float*)d_in[9];
    const float* be2 = (const float*)d_in[10];
    const float* Wl2 = (const float*)d_in[11];
    const float* bl2 = (const float*)d_in[12];
    const float* Wr2 = (const float*)d_in[13];
    const float* br2 = (const float*)d_in[14];
    const float* Wp1 = (const float*)d_in[15];
    const float* bp1 = (const float*)d_in[16];
    const float* Wp2 = (const float*)d_in[17];
    const float* bp2 = (const float*)d_in[18];
    float* out = (float*)d_out;

    const int* src = ei;
    const int* dst = ei + N_EDGES;

    char* ws = (char*)d_ws;
    int*   cnt     = (int*)(ws + 0);           // 409600
    int*   scanout = (int*)(ws + 409600);      // 409600
    int*   bsum    = (int*)(ws + 819200);      // 8192
    int*   rowptr  = (int*)(ws + 827392);      // 409600 (N+1 ints)
    int*   cur     = (int*)(ws + 1236992);     // 409600
    int2*  pk      = (int2*)(ws + 1646592);    // 4800512
    float* WeWl1   = (float*)(ws + 6447104);   // 16384
    float* beWl1   = (float*)(ws + 6463488);   // 512
    float* WeWl2   = (float*)(ws + 6464000);   // 16384
    float* beWl2   = (float*)(ws + 6480384);   // 512
    _Float16* eamb = (_Float16*)(ws + 6480896);   // 6.4 MB
    _Float16* xb   = (_Float16*)(ws + 12880896);  // 25.6 MB
    _Float16* meanb= (_Float16*)(ws + 38480896);  // 25.6 MB
    // UV (51.2 MB) aliases xb+meanb (both dead before uv_gemm)
    _Float16* UV   = (_Float16*)(ws + 12880896);
    _Float16* h1b  = (_Float16*)(ws + 64080896);  // 25.6 MB
    _Float16* h2b  = (_Float16*)(ws + 89680896);  // 25.6 MB
    _Float16* Wbs1 = (_Float16*)(ws + 115280896); // 73728
    _Float16* Wbs2 = (_Float16*)(ws + 115354624); // 73728
    _Float16* Wuv  = (_Float16*)(ws + 115428352); // 65536
    int*   pdst    = (int*)(ws + 115493888);      // 2.4 MB

    const int EB = (N_EDGES + 255) / 256;

    // ---- CSR build ----
    hipMemsetAsync(cnt, 0, N_NODES * sizeof(int), stream);
    hist_kernel<<<EB, 256, 0, stream>>>(dst, cnt);
    scan1_kernel<<<NBLK, 256, 0, stream>>>(cnt, scanout, bsum);
    scan2_kernel<<<1, 512, 0, stream>>>(bsum);
    scan3_kernel<<<NBLK, 256, 0, stream>>>(cnt, scanout, bsum, rowptr, cur);
    fill_kernel<<<EB, 256, 0, stream>>>(src, dst, cur, pk, pdst);

    // ---- graph-invariant precompute (batched) ----
    wewl2_kernel<<<33, 256, 0, stream>>>(We1, be1, Wl1, We2, be2, Wl2,
                                         WeWl1, beWl1, WeWl2, beWl2);
    xb_kernel<<<(N_NODES * HIDDEN / 2 + 255) / 256, 256, 0, stream>>>(x, xb);
    wbig2_kernel<<<288, 256, 0, stream>>>(Wl1, Wr1, WeWl1, Wbs1,
                                          Wl2, Wr2, WeWl2, Wbs2);
    wp1uv_swizzle_kernel<<<128, 256, 0, stream>>>(Wp1, Wuv);

    // ---- layer 1 ----
    agg_kernel_t<true><<<N_NODES / 32, 256, 0, stream>>>(xb, rowptr, pk, ea, meanb, eamb);
    node_gemm_kernel<<<(N_NODES + 63) / 64, 256, 0, stream>>>(
        meanb, xb, eamb, Wbs1, rowptr, bl1, br1, beWl1, h1b);

    // ---- layer 2 ----
    agg_kernel_t<false><<<N_NODES / 32, 256, 0, stream>>>(h1b, rowptr, pk, nullptr, meanb, nullptr);
    node_gemm_kernel<<<(N_NODES + 63) / 64, 256, 0, stream>>>(
        meanb, h1b, eamb, Wbs2, rowptr, bl2, br2, beWl2, h2b);

    // ---- edge predictor: UV decomposition + streaming edge pass ----
    uv_gemm_kernel<<<(N_NODES + 63) / 64, 256, 0, stream>>>(h2b, Wuv, bp1, UV);
    edge_pred_kernel<<<N_EDGES / 32, 256, 0, stream>>>(UV, pk, pdst, Wp2, bp2, out);
}

// Round 8
// 438.992 us; speedup vs baseline: 1.1756x; 1.0297x over previous
//
#include <hip/hip_runtime.h>

#define N_NODES 100000
#define N_EDGES 600000
#define IN_DIM 128
#define EDGE_DIM 32
#define HIDDEN 128
#define NUM_CLASSES 2
#define NBLK 391  // ceil(N_NODES/256)

typedef __attribute__((ext_vector_type(4))) float f32x4;
typedef _Float16 f16x2 __attribute__((ext_vector_type(2)));
typedef _Float16 f16x4 __attribute__((ext_vector_type(4)));
typedef _Float16 f16x8 __attribute__((ext_vector_type(8)));

// ===========================================================================
// CSR build
// ===========================================================================
__global__ void hist_kernel(const int* __restrict__ dst, int* __restrict__ cnt) {
    int e = blockIdx.x * blockDim.x + threadIdx.x;
    if (e < N_EDGES) atomicAdd(&cnt[dst[e]], 1);
}

__global__ void scan1_kernel(const int* __restrict__ cnt,
                             int* __restrict__ scanout, int* __restrict__ bsum) {
    __shared__ int s[256];
    int tid = threadIdx.x;
    int i = blockIdx.x * 256 + tid;
    int v = (i < N_NODES) ? cnt[i] : 0;
    s[tid] = v;
    __syncthreads();
#pragma unroll
    for (int off = 1; off < 256; off <<= 1) {
        int t = 0;
        if (tid >= off) t = s[tid - off];
        __syncthreads();
        if (tid >= off) s[tid] += t;
        __syncthreads();
    }
    if (i < N_NODES) scanout[i] = s[tid];
    if (tid == 255) bsum[blockIdx.x] = s[255];
}

__global__ void scan2_kernel(int* __restrict__ bsum) {
    __shared__ int s[512];
    int tid = threadIdx.x;
    int v = (tid < NBLK) ? bsum[tid] : 0;
    s[tid] = v;
    __syncthreads();
#pragma unroll
    for (int off = 1; off < 512; off <<= 1) {
        int t = 0;
        if (tid >= off) t = s[tid - off];
        __syncthreads();
        if (tid >= off) s[tid] += t;
        __syncthreads();
    }
    if (tid < NBLK) bsum[tid] = s[tid] - v;  // exclusive
}

__global__ void scan3_kernel(const int* __restrict__ cnt,
                             const int* __restrict__ scanout,
                             const int* __restrict__ bsum,
                             int* __restrict__ rowptr, int* __restrict__ cur) {
    int i = blockIdx.x * 256 + threadIdx.x;
    if (i < N_NODES) {
        int excl = scanout[i] + bsum[i >> 8] - cnt[i];
        rowptr[i] = excl;
        cur[i] = excl;
    }
    if (i == 0) rowptr[N_NODES] = N_EDGES;
}

// pk[pos] = { src, edge id } ; pdst[pos] = dst
__global__ void fill_kernel(const int* __restrict__ src, const int* __restrict__ dst,
                            int* __restrict__ cur, int2* __restrict__ pk,
                            int* __restrict__ pdst) {
    int e = blockIdx.x * blockDim.x + threadIdx.x;
    if (e < N_EDGES) {
        int d = dst[e];
        int pos = atomicAdd(&cur[d], 1);
        int2 v;
        v.x = src[e];
        v.y = e;
        pk[pos] = v;
        pdst[pos] = d;
    }
}

// ===========================================================================
// x -> fp16 copy
// ===========================================================================
__global__ void xb_kernel(const float* __restrict__ x, _Float16* __restrict__ xb) {
    int i = blockIdx.x * 256 + threadIdx.x;  // over N*H/2 float2
    if (i < N_NODES * HIDDEN / 2) {
        float2 v = ((const float2*)x)[i];
        f16x2 o;
        o.x = (_Float16)v.x;
        o.y = (_Float16)v.y;
        *(f16x2*)&xb[i * 2] = o;
    }
}

// ===========================================================================
// Both layers batched: WeWl = We @ Wl (32x128), beWl = be @ Wl (128)
// ===========================================================================
__global__ void wewl2_kernel(const float* __restrict__ We1, const float* __restrict__ be1,
                             const float* __restrict__ Wl1,
                             const float* __restrict__ We2, const float* __restrict__ be2,
                             const float* __restrict__ Wl2,
                             float* __restrict__ WeWl1, float* __restrict__ beWl1,
                             float* __restrict__ WeWl2, float* __restrict__ beWl2) {
    int idx0 = blockIdx.x * 256 + threadIdx.x;
    if (idx0 >= 2 * 33 * 128) return;
    int layer = idx0 >= 33 * 128;
    int idx = idx0 - layer * 33 * 128;
    const float* We = layer ? We2 : We1;
    const float* be = layer ? be2 : be1;
    const float* Wl = layer ? Wl2 : Wl1;
    float* WeWl = layer ? WeWl2 : WeWl1;
    float* beWl = layer ? beWl2 : beWl1;
    int r = idx >> 7;
    int n = idx & 127;
    float s = 0.f;
    if (r < 32) {
        for (int j = 0; j < 128; ++j) s += We[r * 128 + j] * Wl[j * 128 + n];
        WeWl[r * 128 + n] = s;
    } else {
        for (int j = 0; j < 128; ++j) s += be[j] * Wl[j * 128 + n];
        beWl[n] = s;
    }
}

// ===========================================================================
// Both layers batched: Wbig = [Wl;Wr;WeWl] -> fp16 MFMA B-frag order, K=288.
// ===========================================================================
__global__ void wbig2_kernel(const float* __restrict__ Wl1, const float* __restrict__ Wr1,
                             const float* __restrict__ WeWl1, _Float16* __restrict__ Wbs1,
                             const float* __restrict__ Wl2, const float* __restrict__ Wr2,
                             const float* __restrict__ WeWl2, _Float16* __restrict__ Wbs2) {
    int idx0 = blockIdx.x * 256 + threadIdx.x;
    if (idx0 >= 2 * 36864) return;
    int layer = idx0 >= 36864;
    int idx = idx0 - layer * 36864;
    const float* Wl = layer ? Wl2 : Wl1;
    const float* Wr = layer ? Wr2 : Wr1;
    const float* WeWl = layer ? WeWl2 : WeWl1;
    _Float16* Wbs = layer ? Wbs2 : Wbs1;
    int j = idx & 7;
    int lane = (idx >> 3) & 63;
    int rem = idx >> 9;  // 0..71
    int ks = rem % 9;
    int nt = rem / 9;
    int k = ks * 32 + ((lane >> 4) & 3) * 8 + j;
    int n = nt * 16 + (lane & 15);
    float v = (k < 128) ? Wl[k * 128 + n]
            : (k < 256) ? Wr[(k - 128) * 128 + n]
                        : WeWl[(k - 256) * 128 + n];
    Wbs[idx] = (_Float16)v;
}

// ===========================================================================
// Per-wave VGPR aggregation, PAIRED wide-issue: lanes 0..31 gather even
// edges, 32..63 odd edges, f16x4/lane (2 rows per load instr — half the
// VMEM+shuffle issues of r2's form, same bytes). 8 nodes/wave in 2 groups
// of 4 (register budget); cross-half shfl_xor(32) combine before write.
// Do NOT fuse with MFMA GEMM (r4/r6: occupancy collapse, regressed).
// ===========================================================================
template <bool EA>
__global__ __launch_bounds__(256) void agg_kernel_t(const _Float16* __restrict__ xin,
                                                    const int* __restrict__ rowptr,
                                                    const int2* __restrict__ pk,
                                                    const float* __restrict__ ea,
                                                    _Float16* __restrict__ meanb,
                                                    _Float16* __restrict__ eamb) {
    int wid = blockIdx.x * 4 + (threadIdx.x >> 6);
    int lane = threadIdx.x & 63;
    int node = lane >> 3;
    int slot = lane & 7;
    int half = lane >> 5;   // 0: even edges, 1: odd edges
    int l32 = lane & 31;    // covers cols l32*4 .. l32*4+3
    int n0 = wid * 8;       // N_NODES % 8 == 0

    // rowptr for 9 consecutive nodes in lanes 0..8; pk covers first 8 slots
    // of all 8 nodes (lane = node*8+slot)
    int rp = rowptr[n0 + (lane < 9 ? lane : 8)];
    int s_n = __shfl(rp, node);
    int e_n = __shfl(rp, node + 1);
    int c_n = e_n - s_n; c_n = c_n > 8 ? 8 : c_n;
    int pos = s_n + (slot < c_n ? slot : 0);
    pos = pos < N_EDGES ? pos : N_EDGES - 1;  // d==0 trailing-node clamp
    int2 pv = pk[pos];

#pragma unroll 1
    for (int g = 0; g < 2; ++g) {
        float ax[4][4];
        float eacc[4];
#pragma unroll
        for (int i = 0; i < 4; ++i) {
            ax[i][0] = 0.f; ax[i][1] = 0.f; ax[i][2] = 0.f; ax[i][3] = 0.f;
            if (EA) eacc[i] = 0.f;
        }

        // ---- main: first 8 slots per node, pair loads ----
#pragma unroll
        for (int i = 0; i < 4; ++i) {
            int ni = g * 4 + i;
            int di = __shfl(rp, ni + 1) - __shfl(rp, ni);
            int ci = di > 8 ? 8 : di;
            f16x4 r[4];
#pragma unroll
            for (int u = 0; u < 4; ++u) {
                int s = __shfl(pv.x, ni * 8 + 2 * u + half);
                r[u] = *(const f16x4*)&xin[s * HIDDEN + l32 * 4];
            }
            float gg[4];
            if (EA) {
#pragma unroll
                for (int u = 0; u < 4; ++u) {
                    int eid = __shfl(pv.y, ni * 8 + 2 * u + half);
                    gg[u] = ea[eid * EDGE_DIM + l32];
                }
            }
#pragma unroll
            for (int u = 0; u < 4; ++u) {
                if (2 * u + half < ci) {
                    ax[i][0] += (float)r[u].x; ax[i][1] += (float)r[u].y;
                    ax[i][2] += (float)r[u].z; ax[i][3] += (float)r[u].w;
                    if (EA) eacc[i] += gg[u];
                }
            }
        }

        // ---- residual: degree > 8, chunks of 8 edges, pair loads ----
#pragma unroll
        for (int i = 0; i < 4; ++i) {
            int ni = g * 4 + i;
            int si = __shfl(rp, ni);
            int ei = __shfl(rp, ni + 1);
            int p = si + 8;
            if (p < ei) {
                do {
                    int c = ei - p; c = c > 8 ? 8 : c;
                    int2 pv2 = pk[p + (slot < c ? slot : 0)];
                    f16x4 r[4];
#pragma unroll
                    for (int u = 0; u < 4; ++u) {
                        int s = __shfl(pv2.x, 2 * u + half);
                        r[u] = *(const f16x4*)&xin[s * HIDDEN + l32 * 4];
                    }
                    float gg[4];
                    if (EA) {
#pragma unroll
                        for (int u = 0; u < 4; ++u) {
                            int eid = __shfl(pv2.y, 2 * u + half);
                            gg[u] = ea[eid * EDGE_DIM + l32];
                        }
                    }
#pragma unroll
                    for (int u = 0; u < 4; ++u) {
                        if (2 * u + half < c) {
                            ax[i][0] += (float)r[u].x; ax[i][1] += (float)r[u].y;
                            ax[i][2] += (float)r[u].z; ax[i][3] += (float)r[u].w;
                            if (EA) eacc[i] += gg[u];
                        }
                    }
                    p += c;
                } while (p < ei);
            }
        }

        // ---- combine halves + write (half h writes node 2j+h; compile-time
        // register indices on both ternary arms — no dynamic indexing) ----
        float dinv[4];
#pragma unroll
        for (int i = 0; i < 4; ++i) {
            int ni = g * 4 + i;
            int di = __shfl(rp, ni + 1) - __shfl(rp, ni);
            dinv[i] = 1.f / (float)(di > 1 ? di : 1);
#pragma unroll
            for (int c = 0; c < 4; ++c) ax[i][c] += __shfl_xor(ax[i][c], 32);
            if (EA) eacc[i] += __shfl_xor(eacc[i], 32);
        }
#pragma unroll
        for (int j = 0; j < 2; ++j) {
            float v0 = half ? ax[2 * j + 1][0] : ax[2 * j][0];
            float v1 = half ? ax[2 * j + 1][1] : ax[2 * j][1];
            float v2 = half ? ax[2 * j + 1][2] : ax[2 * j][2];
            float v3 = half ? ax[2 * j + 1][3] : ax[2 * j][3];
            float dv = half ? dinv[2 * j + 1] : dinv[2 * j];
            int nw = n0 + g * 4 + 2 * j + half;
            f16x4 o;
            o.x = (_Float16)(v0 * dv); o.y = (_Float16)(v1 * dv);
            o.z = (_Float16)(v2 * dv); o.w = (_Float16)(v3 * dv);
            *(f16x4*)&meanb[nw * HIDDEN + l32 * 4] = o;
            if (EA) {
                float ev = half ? eacc[2 * j + 1] : eacc[2 * j];
                eamb[nw * EDGE_DIM + l32] = (_Float16)(ev * dv);
            }
        }
    }
}

// ===========================================================================
// Node GEMM via f16 MFMA: out = relu([mean|x|eam] @ [Wl;Wr;WeWl] + bias), K=288.
// nt-SPLIT loop nesting: wave w owns n-tiles {2w, 2w+1} across ALL 64 rows.
// ===========================================================================
#define APITCH 296  // 288 + 8 f16 pad
__global__ __launch_bounds__(256) void node_gemm_kernel(
        const _Float16* __restrict__ meanb,
        const _Float16* __restrict__ xb,
        const _Float16* __restrict__ eamb,
        const _Float16* __restrict__ Wbs,
        const int* __restrict__ rowptr,
        const float* __restrict__ bl, const float* __restrict__ br,
        const float* __restrict__ beWl,
        _Float16* __restrict__ outb) {
    __shared__ _Float16 s_a[64 * APITCH];  // 37888 B
    __shared__ float s_bias[128];
    __shared__ float s_bw[128];
    __shared__ int s_deg[64];
    int t = threadIdx.x;
    int n0 = blockIdx.x * 64;

    if (t < 128) {
        s_bias[t] = bl[t] + br[t];
        s_bw[t] = beWl[t];
    } else if (t < 192) {
        int m = t - 128;
        int n = n0 + m;
        n = n < N_NODES ? n : N_NODES - 1;
        s_deg[m] = rowptr[n + 1] - rowptr[n];
    }
    for (int i = t; i < 64 * 16; i += 256) {
        int row = i >> 4, seg = i & 15;
        int n = n0 + row;
        n = n < N_NODES ? n : N_NODES - 1;
        *(f16x8*)&s_a[row * APITCH + seg * 8] = *(const f16x8*)&meanb[n * HIDDEN + seg * 8];
        *(f16x8*)&s_a[row * APITCH + 128 + seg * 8] = *(const f16x8*)&xb[n * HIDDEN + seg * 8];
    }
    for (int i = t; i < 64 * 4; i += 256) {
        int row = i >> 2, seg = i & 3;
        int n = n0 + row;
        n = n < N_NODES ? n : N_NODES - 1;
        *(f16x8*)&s_a[row * APITCH + 256 + seg * 8] = *(const f16x8*)&eamb[n * EDGE_DIM + seg * 8];
    }
    __syncthreads();

    int wave = t >> 6;
    int lane = t & 63;
    int col = lane & 15;
    int kgrp = lane >> 4;

    f32x4 acc[4][2];  // [row-tile][n-tile within wave's pair]
#pragma unroll
    for (int rt = 0; rt < 4; ++rt) {
        acc[rt][0] = (f32x4){0.f, 0.f, 0.f, 0.f};
        acc[rt][1] = (f32x4){0.f, 0.f, 0.f, 0.f};
    }

    const f16x8* __restrict__ Wb = (const f16x8*)Wbs;
#pragma unroll
    for (int ks = 0; ks < 9; ++ks) {
        f16x8 b0 = Wb[((2 * wave + 0) * 9 + ks) * 64 + lane];
        f16x8 b1 = Wb[((2 * wave + 1) * 9 + ks) * 64 + lane];
#pragma unroll
        for (int rt = 0; rt < 4; ++rt) {
            f16x8 afrag = *(const f16x8*)&s_a[(rt * 16 + col) * APITCH + ks * 32 + kgrp * 8];
            acc[rt][0] = __builtin_amdgcn_mfma_f32_16x16x32_f16(afrag, b0, acc[rt][0], 0, 0, 0);
            acc[rt][1] = __builtin_amdgcn_mfma_f32_16x16x32_f16(afrag, b1, acc[rt][1], 0, 0, 0);
        }
    }

#pragma unroll
    for (int rt = 0; rt < 4; ++rt) {
#pragma unroll
        for (int j = 0; j < 2; ++j) {
            int feat = (2 * wave + j) * 16 + col;
            float b = s_bias[feat];
            float bw = s_bw[feat];
#pragma unroll
            for (int r = 0; r < 4; ++r) {
                int m = rt * 16 + kgrp * 4 + r;
                int n = n0 + m;
                float v = acc[rt][j][r] + b + (s_deg[m] > 0 ? bw : 0.f);
                v = v > 0.f ? v : 0.f;
                if (n < N_NODES) outb[n * HIDDEN + feat] = (_Float16)v;
            }
        }
    }
}

// ===========================================================================
// Wp1 -> UV-GEMM B fragments: K=128 (h dims), N=256 (U cols | V cols).
// ===========================================================================
__global__ void wp1uv_swizzle_kernel(const float* __restrict__ Wp1,
                                     _Float16* __restrict__ Wuv) {
    int idx = blockIdx.x * 256 + threadIdx.x;  // 32768
    if (idx >= 32768) return;
    int j = idx & 7;
    int lane = (idx >> 3) & 63;
    int ks = (idx >> 9) & 3;
    int nt = (idx >> 11) & 15;
    int k = ks * 32 + ((lane >> 4) & 3) * 8 + j;
    int n = nt * 16 + (lane & 15);
    float v = (n < 128) ? Wp1[k * 128 + n] : Wp1[(128 + k) * 128 + (n - 128)];
    Wuv[idx] = (_Float16)v;
}

// ===========================================================================
// UV GEMM: UV[n][0:128] = h[n]@Wp1_top + bp1 ; UV[n][128:256] = h[n]@Wp1_bot.
// nt-SPLIT: wave w owns n-tiles {4w..4w+3} across ALL 64 rows.
// ===========================================================================
#define UPITCH 136  // 128 + 8 f16 pad
__global__ __launch_bounds__(256) void uv_gemm_kernel(
        const _Float16* __restrict__ h,
        const _Float16* __restrict__ Wuv,
        const float* __restrict__ bp1,
        _Float16* __restrict__ UV) {
    __shared__ _Float16 s_a[64 * UPITCH];  // 17408 B
    __shared__ float s_bias[256];
    int t = threadIdx.x;
    int n0 = blockIdx.x * 64;

    s_bias[t] = (t < 128) ? bp1[t] : 0.f;
    for (int i = t; i < 64 * 16; i += 256) {
        int row = i >> 4, seg = i & 15;
        int n = n0 + row;
        n = n < N_NODES ? n : N_NODES - 1;
        *(f16x8*)&s_a[row * UPITCH + seg * 8] = *(const f16x8*)&h[n * HIDDEN + seg * 8];
    }
    __syncthreads();

    int wave = t >> 6;
    int lane = t & 63;
    int col = lane & 15;
    int kgrp = lane >> 4;

    f32x4 acc[4][4];  // [row-tile][n-tile within wave's quad]
#pragma unroll
    for (int rt = 0; rt < 4; ++rt)
#pragma unroll
        for (int j = 0; j < 4; ++j) acc[rt][j] = (f32x4){0.f, 0.f, 0.f, 0.f};

    const f16x8* __restrict__ Wb = (const f16x8*)Wuv;
#pragma unroll
    for (int ks = 0; ks < 4; ++ks) {
        f16x8 bf[4];
#pragma unroll
        for (int j = 0; j < 4; ++j)
            bf[j] = Wb[((4 * wave + j) * 4 + ks) * 64 + lane];
#pragma unroll
        for (int rt = 0; rt < 4; ++rt) {
            f16x8 afrag = *(const f16x8*)&s_a[(rt * 16 + col) * UPITCH + ks * 32 + kgrp * 8];
#pragma unroll
            for (int j = 0; j < 4; ++j)
                acc[rt][j] = __builtin_amdgcn_mfma_f32_16x16x32_f16(afrag, bf[j], acc[rt][j], 0, 0, 0);
        }
    }

#pragma unroll
    for (int rt = 0; rt < 4; ++rt) {
#pragma unroll
        for (int j = 0; j < 4; ++j) {
            int feat = (4 * wave + j) * 16 + col;
            float b = s_bias[feat];
#pragma unroll
            for (int r = 0; r < 4; ++r) {
                int m = rt * 16 + kgrp * 4 + r;
                int n = n0 + m;
                if (n < N_NODES) UV[n * 256 + feat] = (_Float16)(acc[rt][j][r] + b);
            }
        }
    }
}

// ===========================================================================
// Edge predictor, LDS-free, CSR(dst-sorted) order (r2-proven shuffle form):
// out[eid] = relu(U[src] + V[dst]) @ Wp2 + bp2.
// N_EDGES = 32 * 18750 exactly.
// ===========================================================================
__global__ __launch_bounds__(256) void edge_pred_kernel(
        const _Float16* __restrict__ UV,
        const int2* __restrict__ pk,
        const int* __restrict__ pdst,
        const float* __restrict__ Wp2,
        const float* __restrict__ bp2,
        float* __restrict__ out) {
    int t = threadIdx.x;
    int wave = t >> 6;
    int lane = t & 63;
    int slot = lane >> 5;
    int k4 = (lane & 31) * 4;

    float4 wa = *(const float4*)&Wp2[k4 * 2];
    float4 wb = *(const float4*)&Wp2[k4 * 2 + 4];
    float b0 = bp2[0], b1 = bp2[1];

    int e0 = blockIdx.x * 32 + wave * 8;

    int2 pv[4];
    int dn[4];
#pragma unroll
    for (int u = 0; u < 4; ++u) {
        int pos = e0 + 2 * u + slot;
        pv[u] = pk[pos];
        dn[u] = pdst[pos];
    }
    f16x4 uu[4], vv[4];
#pragma unroll
    for (int u = 0; u < 4; ++u) {
        uu[u] = *(const f16x4*)&UV[pv[u].x * 256 + k4];
        vv[u] = *(const f16x4*)&UV[dn[u] * 256 + 128 + k4];
    }

    float p0[4], p1[4];
#pragma unroll
    for (int u = 0; u < 4; ++u) {
        float z0 = (float)uu[u].x + (float)vv[u].x; z0 = z0 > 0.f ? z0 : 0.f;
        float z1 = (float)uu[u].y + (float)vv[u].y; z1 = z1 > 0.f ? z1 : 0.f;
        float z2 = (float)uu[u].z + (float)vv[u].z; z2 = z2 > 0.f ? z2 : 0.f;
        float z3 = (float)uu[u].w + (float)vv[u].w; z3 = z3 > 0.f ? z3 : 0.f;
        p0[u] = z0 * wa.x + z1 * wa.z + z2 * wb.x + z3 * wb.z;
        p1[u] = z0 * wa.y + z1 * wa.w + z2 * wb.y + z3 * wb.w;
    }
#pragma unroll
    for (int m = 1; m < 32; m <<= 1) {
#pragma unroll
        for (int u = 0; u < 4; ++u) {
            p0[u] += __shfl_xor(p0[u], m);
            p1[u] += __shfl_xor(p1[u], m);
        }
    }
    if ((lane & 31) == 0) {
#pragma unroll
        for (int u = 0; u < 4; ++u) {
            float2 o;
            o.x = p0[u] + b0;
            o.y = p1[u] + b1;
            *(float2*)&out[pv[u].y * 2] = o;
        }
    }
}

// ===========================================================================
extern "C" void kernel_launch(void* const* d_in, const int* in_sizes, int n_in,
                              void* d_out, int out_size, void* d_ws, size_t ws_size,
                              hipStream_t stream) {
    const float* x   = (const float*)d_in[0];
    const int*   ei  = (const int*)d_in[1];
    const float* ea  = (const float*)d_in[2];
    const float* We1 = (const float*)d_in[3];
    const float* be1 = (const float*)d_in[4];
    const float* Wl1 = (const float*)d_in[5];
    const float* bl1 = (const float*)d_in[6];
    const float* Wr1 = (const float*)d_in[7];
    const float* br1 = (const float*)d_in[8];
    const float* We2 = (const float*)d_in[9];
    const float* be2 = (const float*)d_in[10];
    const float* Wl2 = (const float*)d_in[11];
    const float* bl2 = (const float*)d_in[12];
    const float* Wr2 = (const float*)d_in[13];
    const float* br2 = (const float*)d_in[14];
    const float* Wp1 = (const float*)d_in[15];
    const float* bp1 = (const float*)d_in[16];
    const float* Wp2 = (const float*)d_in[17];
    const float* bp2 = (const float*)d_in[18];
    float* out = (float*)d_out;

    const int* src = ei;
    const int* dst = ei + N_EDGES;

    char* ws = (char*)d_ws;
    int*   cnt     = (int*)(ws + 0);           // 409600
    int*   scanout = (int*)(ws + 409600);      // 409600
    int*   bsum    = (int*)(ws + 819200);      // 8192
    int*   rowptr  = (int*)(ws + 827392);      // 409600 (N+1 ints)
    int*   cur     = (int*)(ws + 1236992);     // 409600
    int2*  pk      = (int2*)(ws + 1646592);    // 4800512
    float* WeWl1   = (float*)(ws + 6447104);   // 16384
    float* beWl1   = (float*)(ws + 6463488);   // 512
    float* WeWl2   = (float*)(ws + 6464000);   // 16384
    float* beWl2   = (float*)(ws + 6480384);   // 512
    _Float16* eamb = (_Float16*)(ws + 6480896);   // 6.4 MB
    _Float16* xb   = (_Float16*)(ws + 12880896);  // 25.6 MB
    _Float16* meanb= (_Float16*)(ws + 38480896);  // 25.6 MB
    // UV (51.2 MB) aliases xb+meanb (both dead before uv_gemm)
    _Float16* UV   = (_Float16*)(ws + 12880896);
    _Float16* h1b  = (_Float16*)(ws + 64080896);  // 25.6 MB
    _Float16* h2b  = (_Float16*)(ws + 89680896);  // 25.6 MB
    _Float16* Wbs1 = (_Float16*)(ws + 115280896); // 73728
    _Float16* Wbs2 = (_Float16*)(ws + 115354624); // 73728
    _Float16* Wuv  = (_Float16*)(ws + 115428352); // 65536
    int*   pdst    = (int*)(ws + 115493888);      // 2.4 MB

    const int EB = (N_EDGES + 255) / 256;

    // ---- CSR build ----
    hipMemsetAsync(cnt, 0, N_NODES * sizeof(int), stream);
    hist_kernel<<<EB, 256, 0, stream>>>(dst, cnt);
    scan1_kernel<<<NBLK, 256, 0, stream>>>(cnt, scanout, bsum);
    scan2_kernel<<<1, 512, 0, stream>>>(bsum);
    scan3_kernel<<<NBLK, 256, 0, stream>>>(cnt, scanout, bsum, rowptr, cur);
    fill_kernel<<<EB, 256, 0, stream>>>(src, dst, cur, pk, pdst);

    // ---- graph-invariant precompute (batched) ----
    wewl2_kernel<<<33, 256, 0, stream>>>(We1, be1, Wl1, We2, be2, Wl2,
                                         WeWl1, beWl1, WeWl2, beWl2);
    xb_kernel<<<(N_NODES * HIDDEN / 2 + 255) / 256, 256, 0, stream>>>(x, xb);
    wbig2_kernel<<<288, 256, 0, stream>>>(Wl1, Wr1, WeWl1, Wbs1,
                                          Wl2, Wr2, WeWl2, Wbs2);
    wp1uv_swizzle_kernel<<<128, 256, 0, stream>>>(Wp1, Wuv);

    // ---- layer 1 ----
    agg_kernel_t<true><<<N_NODES / 32, 256, 0, stream>>>(xb, rowptr, pk, ea, meanb, eamb);
    node_gemm_kernel<<<(N_NODES + 63) / 64, 256, 0, stream>>>(
        meanb, xb, eamb, Wbs1, rowptr, bl1, br1, beWl1, h1b);

    // ---- layer 2 ----
    agg_kernel_t<false><<<N_NODES / 32, 256, 0, stream>>>(h1b, rowptr, pk, nullptr, meanb, nullptr);
    node_gemm_kernel<<<(N_NODES + 63) / 64, 256, 0, stream>>>(
        meanb, h1b, eamb, Wbs2, rowptr, bl2, br2, beWl2, h2b);

    // ---- edge predictor: UV decomposition + streaming edge pass ----
    uv_gemm_kernel<<<(N_NODES + 63) / 64, 256, 0, stream>>>(h2b, Wuv, bp1, UV);
    edge_pred_kernel<<<N_EDGES / 32, 256, 0, stream>>>(UV, pk, pdst, Wp2, bp2, out);
}

// Round 9
// 430.292 us; speedup vs baseline: 1.1993x; 1.0202x over previous
//
#include <hip/hip_runtime.h>

#define N_NODES 100000
#define N_EDGES 600000
#define IN_DIM 128
#define EDGE_DIM 32
#define HIDDEN 128
#define NUM_CLASSES 2
#define NBLK 391  // ceil(N_NODES/256)

typedef __attribute__((ext_vector_type(4))) float f32x4;
typedef _Float16 f16x2 __attribute__((ext_vector_type(2)));
typedef _Float16 f16x4 __attribute__((ext_vector_type(4)));
typedef _Float16 f16x8 __attribute__((ext_vector_type(8)));

// ===========================================================================
// CSR build
// ===========================================================================
__global__ void hist_kernel(const int* __restrict__ dst, int* __restrict__ cnt) {
    int e = blockIdx.x * blockDim.x + threadIdx.x;
    if (e < N_EDGES) atomicAdd(&cnt[dst[e]], 1);
}

__global__ void scan1_kernel(const int* __restrict__ cnt,
                             int* __restrict__ scanout, int* __restrict__ bsum) {
    __shared__ int s[256];
    int tid = threadIdx.x;
    int i = blockIdx.x * 256 + tid;
    int v = (i < N_NODES) ? cnt[i] : 0;
    s[tid] = v;
    __syncthreads();
#pragma unroll
    for (int off = 1; off < 256; off <<= 1) {
        int t = 0;
        if (tid >= off) t = s[tid - off];
        __syncthreads();
        if (tid >= off) s[tid] += t;
        __syncthreads();
    }
    if (i < N_NODES) scanout[i] = s[tid];
    if (tid == 255) bsum[blockIdx.x] = s[255];
}

__global__ void scan2_kernel(int* __restrict__ bsum) {
    __shared__ int s[512];
    int tid = threadIdx.x;
    int v = (tid < NBLK) ? bsum[tid] : 0;
    s[tid] = v;
    __syncthreads();
#pragma unroll
    for (int off = 1; off < 512; off <<= 1) {
        int t = 0;
        if (tid >= off) t = s[tid - off];
        __syncthreads();
        if (tid >= off) s[tid] += t;
        __syncthreads();
    }
    if (tid < NBLK) bsum[tid] = s[tid] - v;  // exclusive
}

__global__ void scan3_kernel(const int* __restrict__ cnt,
                             const int* __restrict__ scanout,
                             const int* __restrict__ bsum,
                             int* __restrict__ rowptr, int* __restrict__ cur) {
    int i = blockIdx.x * 256 + threadIdx.x;
    if (i < N_NODES) {
        int excl = scanout[i] + bsum[i >> 8] - cnt[i];
        rowptr[i] = excl;
        cur[i] = excl;
    }
    if (i == 0) rowptr[N_NODES] = N_EDGES;
}

// pk[pos] = { src, edge id } ; pdst[pos] = dst
__global__ void fill_kernel(const int* __restrict__ src, const int* __restrict__ dst,
                            int* __restrict__ cur, int2* __restrict__ pk,
                            int* __restrict__ pdst) {
    int e = blockIdx.x * blockDim.x + threadIdx.x;
    if (e < N_EDGES) {
        int d = dst[e];
        int pos = atomicAdd(&cur[d], 1);
        int2 v;
        v.x = src[e];
        v.y = e;
        pk[pos] = v;
        pdst[pos] = d;
    }
}

// ===========================================================================
// x -> fp16 copy
// ===========================================================================
__global__ void xb_kernel(const float* __restrict__ x, _Float16* __restrict__ xb) {
    int i = blockIdx.x * 256 + threadIdx.x;  // over N*H/2 float2
    if (i < N_NODES * HIDDEN / 2) {
        float2 v = ((const float2*)x)[i];
        f16x2 o;
        o.x = (_Float16)v.x;
        o.y = (_Float16)v.y;
        *(f16x2*)&xb[i * 2] = o;
    }
}

// ===========================================================================
// Both layers batched: WeWl = We @ Wl (32x128), beWl = be @ Wl (128)
// ===========================================================================
__global__ void wewl2_kernel(const float* __restrict__ We1, const float* __restrict__ be1,
                             const float* __restrict__ Wl1,
                             const float* __restrict__ We2, const float* __restrict__ be2,
                             const float* __restrict__ Wl2,
                             float* __restrict__ WeWl1, float* __restrict__ beWl1,
                             float* __restrict__ WeWl2, float* __restrict__ beWl2) {
    int idx0 = blockIdx.x * 256 + threadIdx.x;
    if (idx0 >= 2 * 33 * 128) return;
    int layer = idx0 >= 33 * 128;
    int idx = idx0 - layer * 33 * 128;
    const float* We = layer ? We2 : We1;
    const float* be = layer ? be2 : be1;
    const float* Wl = layer ? Wl2 : Wl1;
    float* WeWl = layer ? WeWl2 : WeWl1;
    float* beWl = layer ? beWl2 : beWl1;
    int r = idx >> 7;
    int n = idx & 127;
    float s = 0.f;
    if (r < 32) {
        for (int j = 0; j < 128; ++j) s += We[r * 128 + j] * Wl[j * 128 + n];
        WeWl[r * 128 + n] = s;
    } else {
        for (int j = 0; j < 128; ++j) s += be[j] * Wl[j * 128 + n];
        beWl[n] = s;
    }
}

// ===========================================================================
// Both layers batched: Wbig = [Wl;Wr;WeWl] -> fp16 MFMA B-frag order, K=288.
// ===========================================================================
__global__ void wbig2_kernel(const float* __restrict__ Wl1, const float* __restrict__ Wr1,
                             const float* __restrict__ WeWl1, _Float16* __restrict__ Wbs1,
                             const float* __restrict__ Wl2, const float* __restrict__ Wr2,
                             const float* __restrict__ WeWl2, _Float16* __restrict__ Wbs2) {
    int idx0 = blockIdx.x * 256 + threadIdx.x;
    if (idx0 >= 2 * 36864) return;
    int layer = idx0 >= 36864;
    int idx = idx0 - layer * 36864;
    const float* Wl = layer ? Wl2 : Wl1;
    const float* Wr = layer ? Wr2 : Wr1;
    const float* WeWl = layer ? WeWl2 : WeWl1;
    _Float16* Wbs = layer ? Wbs2 : Wbs1;
    int j = idx & 7;
    int lane = (idx >> 3) & 63;
    int rem = idx >> 9;  // 0..71
    int ks = rem % 9;
    int nt = rem / 9;
    int k = ks * 32 + ((lane >> 4) & 3) * 8 + j;
    int n = nt * 16 + (lane & 15);
    float v = (k < 128) ? Wl[k * 128 + n]
            : (k < 256) ? Wr[(k - 128) * 128 + n]
                        : WeWl[(k - 256) * 128 + n];
    Wbs[idx] = (_Float16)v;
}

// ===========================================================================
// Per-wave VGPR aggregation, PAIRED wide-issue (r8-proven, VGPR 32):
// lanes 0..31 gather even edges, 32..63 odd edges, f16x4/lane.
// Do NOT fuse with MFMA GEMM (r4/r6: occupancy collapse, regressed).
// ===========================================================================
template <bool EA>
__global__ __launch_bounds__(256) void agg_kernel_t(const _Float16* __restrict__ xin,
                                                    const int* __restrict__ rowptr,
                                                    const int2* __restrict__ pk,
                                                    const float* __restrict__ ea,
                                                    _Float16* __restrict__ meanb,
                                                    _Float16* __restrict__ eamb) {
    int wid = blockIdx.x * 4 + (threadIdx.x >> 6);
    int lane = threadIdx.x & 63;
    int node = lane >> 3;
    int slot = lane & 7;
    int half = lane >> 5;   // 0: even edges, 1: odd edges
    int l32 = lane & 31;    // covers cols l32*4 .. l32*4+3
    int n0 = wid * 8;       // N_NODES % 8 == 0

    int rp = rowptr[n0 + (lane < 9 ? lane : 8)];
    int s_n = __shfl(rp, node);
    int e_n = __shfl(rp, node + 1);
    int c_n = e_n - s_n; c_n = c_n > 8 ? 8 : c_n;
    int pos = s_n + (slot < c_n ? slot : 0);
    pos = pos < N_EDGES ? pos : N_EDGES - 1;  // d==0 trailing-node clamp
    int2 pv = pk[pos];

#pragma unroll 1
    for (int g = 0; g < 2; ++g) {
        float ax[4][4];
        float eacc[4];
#pragma unroll
        for (int i = 0; i < 4; ++i) {
            ax[i][0] = 0.f; ax[i][1] = 0.f; ax[i][2] = 0.f; ax[i][3] = 0.f;
            if (EA) eacc[i] = 0.f;
        }

        // ---- main: first 8 slots per node, pair loads ----
#pragma unroll
        for (int i = 0; i < 4; ++i) {
            int ni = g * 4 + i;
            int di = __shfl(rp, ni + 1) - __shfl(rp, ni);
            int ci = di > 8 ? 8 : di;
            f16x4 r[4];
#pragma unroll
            for (int u = 0; u < 4; ++u) {
                int s = __shfl(pv.x, ni * 8 + 2 * u + half);
                r[u] = *(const f16x4*)&xin[s * HIDDEN + l32 * 4];
            }
            float gg[4];
            if (EA) {
#pragma unroll
                for (int u = 0; u < 4; ++u) {
                    int eid = __shfl(pv.y, ni * 8 + 2 * u + half);
                    gg[u] = ea[eid * EDGE_DIM + l32];
                }
            }
#pragma unroll
            for (int u = 0; u < 4; ++u) {
                if (2 * u + half < ci) {
                    ax[i][0] += (float)r[u].x; ax[i][1] += (float)r[u].y;
                    ax[i][2] += (float)r[u].z; ax[i][3] += (float)r[u].w;
                    if (EA) eacc[i] += gg[u];
                }
            }
        }

        // ---- residual: degree > 8, chunks of 8 edges, pair loads ----
#pragma unroll
        for (int i = 0; i < 4; ++i) {
            int ni = g * 4 + i;
            int si = __shfl(rp, ni);
            int ei = __shfl(rp, ni + 1);
            int p = si + 8;
            if (p < ei) {
                do {
                    int c = ei - p; c = c > 8 ? 8 : c;
                    int2 pv2 = pk[p + (slot < c ? slot : 0)];
                    f16x4 r[4];
#pragma unroll
                    for (int u = 0; u < 4; ++u) {
                        int s = __shfl(pv2.x, 2 * u + half);
                        r[u] = *(const f16x4*)&xin[s * HIDDEN + l32 * 4];
                    }
                    float gg[4];
                    if (EA) {
#pragma unroll
                        for (int u = 0; u < 4; ++u) {
                            int eid = __shfl(pv2.y, 2 * u + half);
                            gg[u] = ea[eid * EDGE_DIM + l32];
                        }
                    }
#pragma unroll
                    for (int u = 0; u < 4; ++u) {
                        if (2 * u + half < c) {
                            ax[i][0] += (float)r[u].x; ax[i][1] += (float)r[u].y;
                            ax[i][2] += (float)r[u].z; ax[i][3] += (float)r[u].w;
                            if (EA) eacc[i] += gg[u];
                        }
                    }
                    p += c;
                } while (p < ei);
            }
        }

        // ---- combine halves + write ----
        float dinv[4];
#pragma unroll
        for (int i = 0; i < 4; ++i) {
            int ni = g * 4 + i;
            int di = __shfl(rp, ni + 1) - __shfl(rp, ni);
            dinv[i] = 1.f / (float)(di > 1 ? di : 1);
#pragma unroll
            for (int c = 0; c < 4; ++c) ax[i][c] += __shfl_xor(ax[i][c], 32);
            if (EA) eacc[i] += __shfl_xor(eacc[i], 32);
        }
#pragma unroll
        for (int j = 0; j < 2; ++j) {
            float v0 = half ? ax[2 * j + 1][0] : ax[2 * j][0];
            float v1 = half ? ax[2 * j + 1][1] : ax[2 * j][1];
            float v2 = half ? ax[2 * j + 1][2] : ax[2 * j][2];
            float v3 = half ? ax[2 * j + 1][3] : ax[2 * j][3];
            float dv = half ? dinv[2 * j + 1] : dinv[2 * j];
            int nw = n0 + g * 4 + 2 * j + half;
            f16x4 o;
            o.x = (_Float16)(v0 * dv); o.y = (_Float16)(v1 * dv);
            o.z = (_Float16)(v2 * dv); o.w = (_Float16)(v3 * dv);
            *(f16x4*)&meanb[nw * HIDDEN + l32 * 4] = o;
            if (EA) {
                float ev = half ? eacc[2 * j + 1] : eacc[2 * j];
                eamb[nw * EDGE_DIM + l32] = (_Float16)(ev * dv);
            }
        }
    }
}

// ===========================================================================
// Node GEMM via f16 MFMA: out = relu([mean|x|eam] @ [Wl;Wr;WeWl] + bias), K=288.
// nt-SPLIT loop nesting: wave w owns n-tiles {2w, 2w+1} across ALL 64 rows.
// ===========================================================================
#define APITCH 296  // 288 + 8 f16 pad
__global__ __launch_bounds__(256) void node_gemm_kernel(
        const _Float16* __restrict__ meanb,
        const _Float16* __restrict__ xb,
        const _Float16* __restrict__ eamb,
        const _Float16* __restrict__ Wbs,
        const int* __restrict__ rowptr,
        const float* __restrict__ bl, const float* __restrict__ br,
        const float* __restrict__ beWl,
        _Float16* __restrict__ outb) {
    __shared__ _Float16 s_a[64 * APITCH];  // 37888 B
    __shared__ float s_bias[128];
    __shared__ float s_bw[128];
    __shared__ int s_deg[64];
    int t = threadIdx.x;
    int n0 = blockIdx.x * 64;

    if (t < 128) {
        s_bias[t] = bl[t] + br[t];
        s_bw[t] = beWl[t];
    } else if (t < 192) {
        int m = t - 128;
        int n = n0 + m;
        n = n < N_NODES ? n : N_NODES - 1;
        s_deg[m] = rowptr[n + 1] - rowptr[n];
    }
    for (int i = t; i < 64 * 16; i += 256) {
        int row = i >> 4, seg = i & 15;
        int n = n0 + row;
        n = n < N_NODES ? n : N_NODES - 1;
        *(f16x8*)&s_a[row * APITCH + seg * 8] = *(const f16x8*)&meanb[n * HIDDEN + seg * 8];
        *(f16x8*)&s_a[row * APITCH + 128 + seg * 8] = *(const f16x8*)&xb[n * HIDDEN + seg * 8];
    }
    for (int i = t; i < 64 * 4; i += 256) {
        int row = i >> 2, seg = i & 3;
        int n = n0 + row;
        n = n < N_NODES ? n : N_NODES - 1;
        *(f16x8*)&s_a[row * APITCH + 256 + seg * 8] = *(const f16x8*)&eamb[n * EDGE_DIM + seg * 8];
    }
    __syncthreads();

    int wave = t >> 6;
    int lane = t & 63;
    int col = lane & 15;
    int kgrp = lane >> 4;

    f32x4 acc[4][2];  // [row-tile][n-tile within wave's pair]
#pragma unroll
    for (int rt = 0; rt < 4; ++rt) {
        acc[rt][0] = (f32x4){0.f, 0.f, 0.f, 0.f};
        acc[rt][1] = (f32x4){0.f, 0.f, 0.f, 0.f};
    }

    const f16x8* __restrict__ Wb = (const f16x8*)Wbs;
#pragma unroll
    for (int ks = 0; ks < 9; ++ks) {
        f16x8 b0 = Wb[((2 * wave + 0) * 9 + ks) * 64 + lane];
        f16x8 b1 = Wb[((2 * wave + 1) * 9 + ks) * 64 + lane];
#pragma unroll
        for (int rt = 0; rt < 4; ++rt) {
            f16x8 afrag = *(const f16x8*)&s_a[(rt * 16 + col) * APITCH + ks * 32 + kgrp * 8];
            acc[rt][0] = __builtin_amdgcn_mfma_f32_16x16x32_f16(afrag, b0, acc[rt][0], 0, 0, 0);
            acc[rt][1] = __builtin_amdgcn_mfma_f32_16x16x32_f16(afrag, b1, acc[rt][1], 0, 0, 0);
        }
    }

#pragma unroll
    for (int rt = 0; rt < 4; ++rt) {
#pragma unroll
        for (int j = 0; j < 2; ++j) {
            int feat = (2 * wave + j) * 16 + col;
            float b = s_bias[feat];
            float bw = s_bw[feat];
#pragma unroll
            for (int r = 0; r < 4; ++r) {
                int m = rt * 16 + kgrp * 4 + r;
                int n = n0 + m;
                float v = acc[rt][j][r] + b + (s_deg[m] > 0 ? bw : 0.f);
                v = v > 0.f ? v : 0.f;
                if (n < N_NODES) outb[n * HIDDEN + feat] = (_Float16)v;
            }
        }
    }
}

// ===========================================================================
// Wp1 -> UV-GEMM B fragments (idx<32768), Wp2 -> zero-padded 16x16x32
// B fragments for the MFMA edge predictor (idx 32768..34815).
// ===========================================================================
__global__ void wp1uv_swizzle_kernel(const float* __restrict__ Wp1,
                                     const float* __restrict__ Wp2,
                                     _Float16* __restrict__ Wuv,
                                     _Float16* __restrict__ Wp2b) {
    int idx = blockIdx.x * 256 + threadIdx.x;
    if (idx < 32768) {
        int j = idx & 7;
        int lane = (idx >> 3) & 63;
        int ks = (idx >> 9) & 3;
        int nt = (idx >> 11) & 15;
        int k = ks * 32 + ((lane >> 4) & 3) * 8 + j;
        int n = nt * 16 + (lane & 15);
        float v = (n < 128) ? Wp1[k * 128 + n] : Wp1[(128 + k) * 128 + (n - 128)];
        Wuv[idx] = (_Float16)v;
    } else if (idx < 32768 + 2048) {
        int r = idx - 32768;
        int j = r & 7;
        int lane = (r >> 3) & 63;
        int ks = r >> 9;  // 0..3
        int k = ks * 32 + ((lane >> 4) & 3) * 8 + j;
        int col = lane & 15;
        Wp2b[r] = (col < 2) ? (_Float16)Wp2[k * 2 + col] : (_Float16)0;
    }
}

// ===========================================================================
// UV GEMM: UV[n][0:128] = h[n]@Wp1_top + bp1 ; UV[n][128:256] = h[n]@Wp1_bot.
// nt-SPLIT: wave w owns n-tiles {4w..4w+3} across ALL 64 rows.
// ===========================================================================
#define UPITCH 136  // 128 + 8 f16 pad
__global__ __launch_bounds__(256) void uv_gemm_kernel(
        const _Float16* __restrict__ h,
        const _Float16* __restrict__ Wuv,
        const float* __restrict__ bp1,
        _Float16* __restrict__ UV) {
    __shared__ _Float16 s_a[64 * UPITCH];  // 17408 B
    __shared__ float s_bias[256];
    int t = threadIdx.x;
    int n0 = blockIdx.x * 64;

    s_bias[t] = (t < 128) ? bp1[t] : 0.f;
    for (int i = t; i < 64 * 16; i += 256) {
        int row = i >> 4, seg = i & 15;
        int n = n0 + row;
        n = n < N_NODES ? n : N_NODES - 1;
        *(f16x8*)&s_a[row * UPITCH + seg * 8] = *(const f16x8*)&h[n * HIDDEN + seg * 8];
    }
    __syncthreads();

    int wave = t >> 6;
    int lane = t & 63;
    int col = lane & 15;
    int kgrp = lane >> 4;

    f32x4 acc[4][4];  // [row-tile][n-tile within wave's quad]
#pragma unroll
    for (int rt = 0; rt < 4; ++rt)
#pragma unroll
        for (int j = 0; j < 4; ++j) acc[rt][j] = (f32x4){0.f, 0.f, 0.f, 0.f};

    const f16x8* __restrict__ Wb = (const f16x8*)Wuv;
#pragma unroll
    for (int ks = 0; ks < 4; ++ks) {
        f16x8 bf[4];
#pragma unroll
        for (int j = 0; j < 4; ++j)
            bf[j] = Wb[((4 * wave + j) * 4 + ks) * 64 + lane];
#pragma unroll
        for (int rt = 0; rt < 4; ++rt) {
            f16x8 afrag = *(const f16x8*)&s_a[(rt * 16 + col) * UPITCH + ks * 32 + kgrp * 8];
#pragma unroll
            for (int j = 0; j < 4; ++j)
                acc[rt][j] = __builtin_amdgcn_mfma_f32_16x16x32_f16(afrag, bf[j], acc[rt][j], 0, 0, 0);
        }
    }

#pragma unroll
    for (int rt = 0; rt < 4; ++rt) {
#pragma unroll
        for (int j = 0; j < 4; ++j) {
            int feat = (4 * wave + j) * 16 + col;
            float b = s_bias[feat];
#pragma unroll
            for (int r = 0; r < 4; ++r) {
                int m = rt * 16 + kgrp * 4 + r;
                int n = n0 + m;
                if (n < N_NODES) UV[n * 256 + feat] = (_Float16)(acc[rt][j][r] + b);
            }
        }
    }
}

// ===========================================================================
// MFMA edge predictor (r4/r5-verified): wave = 16 edges. A-frag =
// relu(U[src]+V[dst]) rows (4 x 16B loads per operand per wave — 2x the
// per-instr width of the shuffle form), B-frag = zero-padded Wp2.
// Replaces the 5-level shuffle tree (40 shfl + 40 FMA / 8 edges) with
// 4 MFMAs + packed f16 adds. N_EDGES = 64 * 9375 exactly.
// ===========================================================================
__global__ __launch_bounds__(256) void edge_pred_kernel(
        const _Float16* __restrict__ UV,
        const int2* __restrict__ pk,
        const int* __restrict__ pdst,
        const _Float16* __restrict__ Wp2b,
        const float* __restrict__ bp2,
        float* __restrict__ out) {
    int t = threadIdx.x;
    int wave = t >> 6;
    int lane = t & 63;
    int row = lane & 15;
    int kgrp = lane >> 4;
    int e0 = blockIdx.x * 64 + wave * 16;

    int2 pv = pk[e0 + row];
    int dn = pdst[e0 + row];
    const _Float16* ubase = &UV[pv.x * 256 + kgrp * 8];
    const _Float16* vbase = &UV[dn * 256 + 128 + kgrp * 8];

    f16x8 au[4], av[4], bf[4];
#pragma unroll
    for (int ks = 0; ks < 4; ++ks) {
        au[ks] = *(const f16x8*)&ubase[ks * 32];
        av[ks] = *(const f16x8*)&vbase[ks * 32];
        bf[ks] = *(const f16x8*)&Wp2b[(ks * 64 + lane) * 8];
    }

    f32x4 acc = (f32x4){0.f, 0.f, 0.f, 0.f};
#pragma unroll
    for (int ks = 0; ks < 4; ++ks) {
        f16x8 z = au[ks] + av[ks];
#pragma unroll
        for (int j = 0; j < 8; ++j) z[j] = z[j] > (_Float16)0 ? z[j] : (_Float16)0;
        acc = __builtin_amdgcn_mfma_f32_16x16x32_f16(z, bf[ks], acc, 0, 0, 0);
    }

    // gather eids for this lane's 4 C-rows (all lanes active for shuffles)
    int eids[4];
#pragma unroll
    for (int r = 0; r < 4; ++r) eids[r] = __shfl(pv.y, kgrp * 4 + r);

    int col = lane & 15;
    if (col < 2) {
        float bb = bp2[col];
#pragma unroll
        for (int r = 0; r < 4; ++r) out[eids[r] * 2 + col] = acc[r] + bb;
    }
}

// ===========================================================================
extern "C" void kernel_launch(void* const* d_in, const int* in_sizes, int n_in,
                              void* d_out, int out_size, void* d_ws, size_t ws_size,
                              hipStream_t stream) {
    const float* x   = (const float*)d_in[0];
    const int*   ei  = (const int*)d_in[1];
    const float* ea  = (const float*)d_in[2];
    const float* We1 = (const float*)d_in[3];
    const float* be1 = (const float*)d_in[4];
    const float* Wl1 = (const float*)d_in[5];
    const float* bl1 = (const float*)d_in[6];
    const float* Wr1 = (const float*)d_in[7];
    const float* br1 = (const float*)d_in[8];
    const float* We2 = (const float*)d_in[9];
    const float* be2 = (const float*)d_in[10];
    const float* Wl2 = (const float*)d_in[11];
    const float* bl2 = (const float*)d_in[12];
    const float* Wr2 = (const float*)d_in[13];
    const float* br2 = (const float*)d_in[14];
    const float* Wp1 = (const float*)d_in[15];
    const float* bp1 = (const float*)d_in[16];
    const float* Wp2 = (const float*)d_in[17];
    const float* bp2 = (const float*)d_in[18];
    float* out = (float*)d_out;

    const int* src = ei;
    const int* dst = ei + N_EDGES;

    char* ws = (char*)d_ws;
    int*   cnt     = (int*)(ws + 0);           // 409600
    int*   scanout = (int*)(ws + 409600);      // 409600 (dead after scan3)
    int*   bsum    = (int*)(ws + 819200);      // 8192
    int*   rowptr  = (int*)(ws + 827392);      // 409600 (N+1 ints)
    int*   cur     = (int*)(ws + 1236992);     // 409600
    int2*  pk      = (int2*)(ws + 1646592);    // 4800512
    float* WeWl1   = (float*)(ws + 6447104);   // 16384
    float* beWl1   = (float*)(ws + 6463488);   // 512
    float* WeWl2   = (float*)(ws + 6464000);   // 16384
    float* beWl2   = (float*)(ws + 6480384);   // 512
    _Float16* eamb = (_Float16*)(ws + 6480896);   // 6.4 MB
    _Float16* xb   = (_Float16*)(ws + 12880896);  // 25.6 MB
    _Float16* meanb= (_Float16*)(ws + 38480896);  // 25.6 MB
    // UV (51.2 MB) aliases xb+meanb (both dead before uv_gemm)
    _Float16* UV   = (_Float16*)(ws + 12880896);
    _Float16* h1b  = (_Float16*)(ws + 64080896);  // 25.6 MB
    _Float16* h2b  = (_Float16*)(ws + 89680896);  // 25.6 MB
    _Float16* Wbs1 = (_Float16*)(ws + 115280896); // 73728
    _Float16* Wbs2 = (_Float16*)(ws + 115354624); // 73728
    _Float16* Wuv  = (_Float16*)(ws + 115428352); // 65536
    int*   pdst    = (int*)(ws + 115493888);      // 2.4 MB
    // Wp2b (4 KB) reuses the scanout region (dead once wp1uv runs)
    _Float16* Wp2b = (_Float16*)(ws + 409600);

    const int EB = (N_EDGES + 255) / 256;

    // ---- CSR build ----
    hipMemsetAsync(cnt, 0, N_NODES * sizeof(int), stream);
    hist_kernel<<<EB, 256, 0, stream>>>(dst, cnt);
    scan1_kernel<<<NBLK, 256, 0, stream>>>(cnt, scanout, bsum);
    scan2_kernel<<<1, 512, 0, stream>>>(bsum);
    scan3_kernel<<<NBLK, 256, 0, stream>>>(cnt, scanout, bsum, rowptr, cur);
    fill_kernel<<<EB, 256, 0, stream>>>(src, dst, cur, pk, pdst);

    // ---- graph-invariant precompute (batched) ----
    wewl2_kernel<<<33, 256, 0, stream>>>(We1, be1, Wl1, We2, be2, Wl2,
                                         WeWl1, beWl1, WeWl2, beWl2);
    xb_kernel<<<(N_NODES * HIDDEN / 2 + 255) / 256, 256, 0, stream>>>(x, xb);
    wbig2_kernel<<<288, 256, 0, stream>>>(Wl1, Wr1, WeWl1, Wbs1,
                                          Wl2, Wr2, WeWl2, Wbs2);
    wp1uv_swizzle_kernel<<<136, 256, 0, stream>>>(Wp1, Wp2, Wuv, Wp2b);

    // ---- layer 1 ----
    agg_kernel_t<true><<<N_NODES / 32, 256, 0, stream>>>(xb, rowptr, pk, ea, meanb, eamb);
    node_gemm_kernel<<<(N_NODES + 63) / 64, 256, 0, stream>>>(
        meanb, xb, eamb, Wbs1, rowptr, bl1, br1, beWl1, h1b);

    // ---- layer 2 ----
    agg_kernel_t<false><<<N_NODES / 32, 256, 0, stream>>>(h1b, rowptr, pk, nullptr, meanb, nullptr);
    node_gemm_kernel<<<(N_NODES + 63) / 64, 256, 0, stream>>>(
        meanb, h1b, eamb, Wbs2, rowptr, bl2, br2, beWl2, h2b);

    // ---- edge predictor: UV decomposition + MFMA edge pass ----
    uv_gemm_kernel<<<(N_NODES + 63) / 64, 256, 0, stream>>>(h2b, Wuv, bp1, UV);
    edge_pred_kernel<<<N_EDGES / 64, 256, 0, stream>>>(UV, pk, pdst, Wp2b, bp2, out);
}

// Round 10
// 429.981 us; speedup vs baseline: 1.2002x; 1.0007x over previous
//
#include <hip/hip_runtime.h>

#define N_NODES 100000
#define N_EDGES 600000
#define IN_DIM 128
#define EDGE_DIM 32
#define HIDDEN 128
#define NUM_CLASSES 2
#define NBLK 391  // ceil(N_NODES/256)

typedef __attribute__((ext_vector_type(4))) float f32x4;
typedef _Float16 f16x2 __attribute__((ext_vector_type(2)));
typedef _Float16 f16x4 __attribute__((ext_vector_type(4)));
typedef _Float16 f16x8 __attribute__((ext_vector_type(8)));

// ===========================================================================
// CSR build
// ===========================================================================
__global__ void hist_kernel(const int* __restrict__ dst, int* __restrict__ cnt) {
    int e = blockIdx.x * blockDim.x + threadIdx.x;
    if (e < N_EDGES) atomicAdd(&cnt[dst[e]], 1);
}

__global__ void scan1_kernel(const int* __restrict__ cnt,
                             int* __restrict__ scanout, int* __restrict__ bsum) {
    __shared__ int s[256];
    int tid = threadIdx.x;
    int i = blockIdx.x * 256 + tid;
    int v = (i < N_NODES) ? cnt[i] : 0;
    s[tid] = v;
    __syncthreads();
#pragma unroll
    for (int off = 1; off < 256; off <<= 1) {
        int t = 0;
        if (tid >= off) t = s[tid - off];
        __syncthreads();
        if (tid >= off) s[tid] += t;
        __syncthreads();
    }
    if (i < N_NODES) scanout[i] = s[tid];
    if (tid == 255) bsum[blockIdx.x] = s[255];
}

__global__ void scan2_kernel(int* __restrict__ bsum) {
    __shared__ int s[512];
    int tid = threadIdx.x;
    int v = (tid < NBLK) ? bsum[tid] : 0;
    s[tid] = v;
    __syncthreads();
#pragma unroll
    for (int off = 1; off < 512; off <<= 1) {
        int t = 0;
        if (tid >= off) t = s[tid - off];
        __syncthreads();
        if (tid >= off) s[tid] += t;
        __syncthreads();
    }
    if (tid < NBLK) bsum[tid] = s[tid] - v;  // exclusive
}

__global__ void scan3_kernel(const int* __restrict__ cnt,
                             const int* __restrict__ scanout,
                             const int* __restrict__ bsum,
                             int* __restrict__ rowptr, int* __restrict__ cur) {
    int i = blockIdx.x * 256 + threadIdx.x;
    if (i < N_NODES) {
        int excl = scanout[i] + bsum[i >> 8] - cnt[i];
        rowptr[i] = excl;
        cur[i] = excl;
    }
    if (i == 0) rowptr[N_NODES] = N_EDGES;
}

// pk[pos] = { src, edge id } ; pdst[pos] = dst
__global__ void fill_kernel(const int* __restrict__ src, const int* __restrict__ dst,
                            int* __restrict__ cur, int2* __restrict__ pk,
                            int* __restrict__ pdst) {
    int e = blockIdx.x * blockDim.x + threadIdx.x;
    if (e < N_EDGES) {
        int d = dst[e];
        int pos = atomicAdd(&cur[d], 1);
        int2 v;
        v.x = src[e];
        v.y = e;
        pk[pos] = v;
        pdst[pos] = d;
    }
}

// ===========================================================================
// x -> fp16 copy
// ===========================================================================
__global__ void xb_kernel(const float* __restrict__ x, _Float16* __restrict__ xb) {
    int i = blockIdx.x * 256 + threadIdx.x;  // over N*H/2 float2
    if (i < N_NODES * HIDDEN / 2) {
        float2 v = ((const float2*)x)[i];
        f16x2 o;
        o.x = (_Float16)v.x;
        o.y = (_Float16)v.y;
        *(f16x2*)&xb[i * 2] = o;
    }
}

// ===========================================================================
// Both layers batched: WeWl = We @ Wl (32x128), beWl = be @ Wl (128)
// ===========================================================================
__global__ void wewl2_kernel(const float* __restrict__ We1, const float* __restrict__ be1,
                             const float* __restrict__ Wl1,
                             const float* __restrict__ We2, const float* __restrict__ be2,
                             const float* __restrict__ Wl2,
                             float* __restrict__ WeWl1, float* __restrict__ beWl1,
                             float* __restrict__ WeWl2, float* __restrict__ beWl2) {
    int idx0 = blockIdx.x * 256 + threadIdx.x;
    if (idx0 >= 2 * 33 * 128) return;
    int layer = idx0 >= 33 * 128;
    int idx = idx0 - layer * 33 * 128;
    const float* We = layer ? We2 : We1;
    const float* be = layer ? be2 : be1;
    const float* Wl = layer ? Wl2 : Wl1;
    float* WeWl = layer ? WeWl2 : WeWl1;
    float* beWl = layer ? beWl2 : beWl1;
    int r = idx >> 7;
    int n = idx & 127;
    float s = 0.f;
    if (r < 32) {
        for (int j = 0; j < 128; ++j) s += We[r * 128 + j] * Wl[j * 128 + n];
        WeWl[r * 128 + n] = s;
    } else {
        for (int j = 0; j < 128; ++j) s += be[j] * Wl[j * 128 + n];
        beWl[n] = s;
    }
}

// ===========================================================================
// Both layers batched: Wbig = [Wl;Wr;WeWl] -> fp16 MFMA B-frag order, K=288.
// ===========================================================================
__global__ void wbig2_kernel(const float* __restrict__ Wl1, const float* __restrict__ Wr1,
                             const float* __restrict__ WeWl1, _Float16* __restrict__ Wbs1,
                             const float* __restrict__ Wl2, const float* __restrict__ Wr2,
                             const float* __restrict__ WeWl2, _Float16* __restrict__ Wbs2) {
    int idx0 = blockIdx.x * 256 + threadIdx.x;
    if (idx0 >= 2 * 36864) return;
    int layer = idx0 >= 36864;
    int idx = idx0 - layer * 36864;
    const float* Wl = layer ? Wl2 : Wl1;
    const float* Wr = layer ? Wr2 : Wr1;
    const float* WeWl = layer ? WeWl2 : WeWl1;
    _Float16* Wbs = layer ? Wbs2 : Wbs1;
    int j = idx & 7;
    int lane = (idx >> 3) & 63;
    int rem = idx >> 9;  // 0..71
    int ks = rem % 9;
    int nt = rem / 9;
    int k = ks * 32 + ((lane >> 4) & 3) * 8 + j;
    int n = nt * 16 + (lane & 15);
    float v = (k < 128) ? Wl[k * 128 + n]
            : (k < 256) ? Wr[(k - 128) * 128 + n]
                        : WeWl[(k - 256) * 128 + n];
    Wbs[idx] = (_Float16)v;
}

// ===========================================================================
// Per-wave VGPR aggregation, GROUP-PER-NODE quad loads:
// 4 groups of 16 lanes; 16 lanes x f16x8 = one full 256B x-row, so each
// load instruction fetches 4 edges' rows (1KB/instr). Group q OWNS window
// nodes {2q, 2q+1} — no cross-lane combine at all (r8's shfl_xor gone).
// Broadcasts via runtime-lane __shfl (ds_bpermute). Residual (deg>8) is a
// group-divergent loop with per-lane pk loads (no shuffles under
// divergence), 4-deep chunks for MLP.
// Do NOT fuse with MFMA GEMM (r4/r6: occupancy collapse, regressed).
// ===========================================================================
template <bool EA>
__global__ __launch_bounds__(256) void agg_kernel_t(const _Float16* __restrict__ xin,
                                                    const int* __restrict__ rowptr,
                                                    const int2* __restrict__ pk,
                                                    const float* __restrict__ ea,
                                                    _Float16* __restrict__ meanb,
                                                    _Float16* __restrict__ eamb) {
    int wid = blockIdx.x * 4 + (threadIdx.x >> 6);
    int lane = threadIdx.x & 63;
    int node = lane >> 3;   // for pk prefetch
    int slot = lane & 7;    // for pk prefetch
    int q = lane >> 4;      // group 0..3; owns window nodes 2q, 2q+1
    int l16 = lane & 15;    // covers x cols l16*8..+7, ea cols l16*2..+1
    int n0 = wid * 8;       // N_NODES % 8 == 0

    // rowptr for 9 consecutive nodes in lanes 0..8; pk prefetch covers
    // first 8 slots of all 8 nodes (lane = node*8 + slot)
    int rp = rowptr[n0 + (lane < 9 ? lane : 8)];
    int s_n = __shfl(rp, node);
    int e_n = __shfl(rp, node + 1);
    int c_n = e_n - s_n; c_n = c_n > 8 ? 8 : c_n;
    int pos = s_n + (slot < c_n ? slot : 0);
    pos = pos < N_EDGES ? pos : N_EDGES - 1;  // d==0 trailing-node clamp
    int2 pv = pk[pos];

    float ax[2][8];
    float ea2[2][2];
#pragma unroll
    for (int j = 0; j < 2; ++j) {
#pragma unroll
        for (int c = 0; c < 8; ++c) ax[j][c] = 0.f;
        if (EA) { ea2[j][0] = 0.f; ea2[j][1] = 0.f; }
    }

    int nj0 = 2 * q;  // window-local first owned node (uniform per group)
    int d0 = __shfl(rp, nj0 + 1) - __shfl(rp, nj0);
    int d1 = __shfl(rp, nj0 + 2) - __shfl(rp, nj0 + 1);

    // ---- main: first 8 slots of each owned node, 2 batches of 4 ----
#pragma unroll
    for (int j = 0; j < 2; ++j) {
        int nj = nj0 + j;
        int dj = j ? d1 : d0;
        int cj = dj > 8 ? 8 : dj;
#pragma unroll
        for (int b = 0; b < 2; ++b) {
            f16x8 r[4];
            float2 g[4];
#pragma unroll
            for (int u = 0; u < 4; ++u) {
                int s = __shfl(pv.x, nj * 8 + b * 4 + u);
                r[u] = *(const f16x8*)&xin[s * HIDDEN + l16 * 8];
            }
            if (EA) {
#pragma unroll
                for (int u = 0; u < 4; ++u) {
                    int eid = __shfl(pv.y, nj * 8 + b * 4 + u);
                    g[u] = *(const float2*)&ea[eid * EDGE_DIM + l16 * 2];
                }
            }
#pragma unroll
            for (int u = 0; u < 4; ++u) {
                if (b * 4 + u < cj) {
#pragma unroll
                    for (int c = 0; c < 8; ++c) ax[j][c] += (float)r[u][c];
                    if (EA) { ea2[j][0] += g[u].x; ea2[j][1] += g[u].y; }
                }
            }
        }
    }

    // ---- residual: deg > 8, group-divergent, per-lane pk loads ----
#pragma unroll
    for (int j = 0; j < 2; ++j) {
        int nj = nj0 + j;
        int sj = __shfl(rp, nj);
        int ej = __shfl(rp, nj + 1);
        int p = sj + 8;
        while (p < ej) {
            int c = ej - p; c = c > 4 ? 4 : c;
            f16x8 r[4];
            float2 g[4];
            int2 pv2[4];
#pragma unroll
            for (int u = 0; u < 4; ++u)
                pv2[u] = pk[p + (u < c ? u : 0)];
#pragma unroll
            for (int u = 0; u < 4; ++u) {
                r[u] = *(const f16x8*)&xin[pv2[u].x * HIDDEN + l16 * 8];
                if (EA) g[u] = *(const float2*)&ea[pv2[u].y * EDGE_DIM + l16 * 2];
            }
#pragma unroll
            for (int u = 0; u < 4; ++u) {
                if (u < c) {
#pragma unroll
                    for (int cc = 0; cc < 8; ++cc) ax[j][cc] += (float)r[u][cc];
                    if (EA) { ea2[j][0] += g[u].x; ea2[j][1] += g[u].y; }
                }
            }
            p += c;
        }
    }

    // ---- write: group-owned, no combine ----
#pragma unroll
    for (int j = 0; j < 2; ++j) {
        int nj = nj0 + j;
        int dj = j ? d1 : d0;
        float dv = 1.f / (float)(dj > 1 ? dj : 1);
        f16x8 o;
#pragma unroll
        for (int c = 0; c < 8; ++c) o[c] = (_Float16)(ax[j][c] * dv);
        *(f16x8*)&meanb[(n0 + nj) * HIDDEN + l16 * 8] = o;
        if (EA) {
            f16x2 eo;
            eo.x = (_Float16)(ea2[j][0] * dv);
            eo.y = (_Float16)(ea2[j][1] * dv);
            *(f16x2*)&eamb[(n0 + nj) * EDGE_DIM + l16 * 2] = eo;
        }
    }
}

// ===========================================================================
// Node GEMM via f16 MFMA: out = relu([mean|x|eam] @ [Wl;Wr;WeWl] + bias), K=288.
// nt-SPLIT loop nesting: wave w owns n-tiles {2w, 2w+1} across ALL 64 rows.
// ===========================================================================
#define APITCH 296  // 288 + 8 f16 pad
__global__ __launch_bounds__(256) void node_gemm_kernel(
        const _Float16* __restrict__ meanb,
        const _Float16* __restrict__ xb,
        const _Float16* __restrict__ eamb,
        const _Float16* __restrict__ Wbs,
        const int* __restrict__ rowptr,
        const float* __restrict__ bl, const float* __restrict__ br,
        const float* __restrict__ beWl,
        _Float16* __restrict__ outb) {
    __shared__ _Float16 s_a[64 * APITCH];  // 37888 B
    __shared__ float s_bias[128];
    __shared__ float s_bw[128];
    __shared__ int s_deg[64];
    int t = threadIdx.x;
    int n0 = blockIdx.x * 64;

    if (t < 128) {
        s_bias[t] = bl[t] + br[t];
        s_bw[t] = beWl[t];
    } else if (t < 192) {
        int m = t - 128;
        int n = n0 + m;
        n = n < N_NODES ? n : N_NODES - 1;
        s_deg[m] = rowptr[n + 1] - rowptr[n];
    }
    for (int i = t; i < 64 * 16; i += 256) {
        int row = i >> 4, seg = i & 15;
        int n = n0 + row;
        n = n < N_NODES ? n : N_NODES - 1;
        *(f16x8*)&s_a[row * APITCH + seg * 8] = *(const f16x8*)&meanb[n * HIDDEN + seg * 8];
        *(f16x8*)&s_a[row * APITCH + 128 + seg * 8] = *(const f16x8*)&xb[n * HIDDEN + seg * 8];
    }
    for (int i = t; i < 64 * 4; i += 256) {
        int row = i >> 2, seg = i & 3;
        int n = n0 + row;
        n = n < N_NODES ? n : N_NODES - 1;
        *(f16x8*)&s_a[row * APITCH + 256 + seg * 8] = *(const f16x8*)&eamb[n * EDGE_DIM + seg * 8];
    }
    __syncthreads();

    int wave = t >> 6;
    int lane = t & 63;
    int col = lane & 15;
    int kgrp = lane >> 4;

    f32x4 acc[4][2];  // [row-tile][n-tile within wave's pair]
#pragma unroll
    for (int rt = 0; rt < 4; ++rt) {
        acc[rt][0] = (f32x4){0.f, 0.f, 0.f, 0.f};
        acc[rt][1] = (f32x4){0.f, 0.f, 0.f, 0.f};
    }

    const f16x8* __restrict__ Wb = (const f16x8*)Wbs;
#pragma unroll
    for (int ks = 0; ks < 9; ++ks) {
        f16x8 b0 = Wb[((2 * wave + 0) * 9 + ks) * 64 + lane];
        f16x8 b1 = Wb[((2 * wave + 1) * 9 + ks) * 64 + lane];
#pragma unroll
        for (int rt = 0; rt < 4; ++rt) {
            f16x8 afrag = *(const f16x8*)&s_a[(rt * 16 + col) * APITCH + ks * 32 + kgrp * 8];
            acc[rt][0] = __builtin_amdgcn_mfma_f32_16x16x32_f16(afrag, b0, acc[rt][0], 0, 0, 0);
            acc[rt][1] = __builtin_amdgcn_mfma_f32_16x16x32_f16(afrag, b1, acc[rt][1], 0, 0, 0);
        }
    }

#pragma unroll
    for (int rt = 0; rt < 4; ++rt) {
#pragma unroll
        for (int j = 0; j < 2; ++j) {
            int feat = (2 * wave + j) * 16 + col;
            float b = s_bias[feat];
            float bw = s_bw[feat];
#pragma unroll
            for (int r = 0; r < 4; ++r) {
                int m = rt * 16 + kgrp * 4 + r;
                int n = n0 + m;
                float v = acc[rt][j][r] + b + (s_deg[m] > 0 ? bw : 0.f);
                v = v > 0.f ? v : 0.f;
                if (n < N_NODES) outb[n * HIDDEN + feat] = (_Float16)v;
            }
        }
    }
}

// ===========================================================================
// Wp1 -> UV-GEMM B fragments (idx<32768), Wp2 -> zero-padded 16x16x32
// B fragments for the MFMA edge predictor (idx 32768..34815).
// ===========================================================================
__global__ void wp1uv_swizzle_kernel(const float* __restrict__ Wp1,
                                     const float* __restrict__ Wp2,
                                     _Float16* __restrict__ Wuv,
                                     _Float16* __restrict__ Wp2b) {
    int idx = blockIdx.x * 256 + threadIdx.x;
    if (idx < 32768) {
        int j = idx & 7;
        int lane = (idx >> 3) & 63;
        int ks = (idx >> 9) & 3;
        int nt = (idx >> 11) & 15;
        int k = ks * 32 + ((lane >> 4) & 3) * 8 + j;
        int n = nt * 16 + (lane & 15);
        float v = (n < 128) ? Wp1[k * 128 + n] : Wp1[(128 + k) * 128 + (n - 128)];
        Wuv[idx] = (_Float16)v;
    } else if (idx < 32768 + 2048) {
        int r = idx - 32768;
        int j = r & 7;
        int lane = (r >> 3) & 63;
        int ks = r >> 9;  // 0..3
        int k = ks * 32 + ((lane >> 4) & 3) * 8 + j;
        int col = lane & 15;
        Wp2b[r] = (col < 2) ? (_Float16)Wp2[k * 2 + col] : (_Float16)0;
    }
}

// ===========================================================================
// UV GEMM: UV[n][0:128] = h[n]@Wp1_top + bp1 ; UV[n][128:256] = h[n]@Wp1_bot.
// nt-SPLIT: wave w owns n-tiles {4w..4w+3} across ALL 64 rows.
// ===========================================================================
#define UPITCH 136  // 128 + 8 f16 pad
__global__ __launch_bounds__(256) void uv_gemm_kernel(
        const _Float16* __restrict__ h,
        const _Float16* __restrict__ Wuv,
        const float* __restrict__ bp1,
        _Float16* __restrict__ UV) {
    __shared__ _Float16 s_a[64 * UPITCH];  // 17408 B
    __shared__ float s_bias[256];
    int t = threadIdx.x;
    int n0 = blockIdx.x * 64;

    s_bias[t] = (t < 128) ? bp1[t] : 0.f;
    for (int i = t; i < 64 * 16; i += 256) {
        int row = i >> 4, seg = i & 15;
        int n = n0 + row;
        n = n < N_NODES ? n : N_NODES - 1;
        *(f16x8*)&s_a[row * UPITCH + seg * 8] = *(const f16x8*)&h[n * HIDDEN + seg * 8];
    }
    __syncthreads();

    int wave = t >> 6;
    int lane = t & 63;
    int col = lane & 15;
    int kgrp = lane >> 4;

    f32x4 acc[4][4];  // [row-tile][n-tile within wave's quad]
#pragma unroll
    for (int rt = 0; rt < 4; ++rt)
#pragma unroll
        for (int j = 0; j < 4; ++j) acc[rt][j] = (f32x4){0.f, 0.f, 0.f, 0.f};

    const f16x8* __restrict__ Wb = (const f16x8*)Wuv;
#pragma unroll
    for (int ks = 0; ks < 4; ++ks) {
        f16x8 bf[4];
#pragma unroll
        for (int j = 0; j < 4; ++j)
            bf[j] = Wb[((4 * wave + j) * 4 + ks) * 64 + lane];
#pragma unroll
        for (int rt = 0; rt < 4; ++rt) {
            f16x8 afrag = *(const f16x8*)&s_a[(rt * 16 + col) * UPITCH + ks * 32 + kgrp * 8];
#pragma unroll
            for (int j = 0; j < 4; ++j)
                acc[rt][j] = __builtin_amdgcn_mfma_f32_16x16x32_f16(afrag, bf[j], acc[rt][j], 0, 0, 0);
        }
    }

#pragma unroll
    for (int rt = 0; rt < 4; ++rt) {
#pragma unroll
        for (int j = 0; j < 4; ++j) {
            int feat = (4 * wave + j) * 16 + col;
            float b = s_bias[feat];
#pragma unroll
            for (int r = 0; r < 4; ++r) {
                int m = rt * 16 + kgrp * 4 + r;
                int n = n0 + m;
                if (n < N_NODES) UV[n * 256 + feat] = (_Float16)(acc[rt][j][r] + b);
            }
        }
    }
}

// ===========================================================================
// MFMA edge predictor (r4/r5/r9-verified): wave = 16 edges. A-frag =
// relu(U[src]+V[dst]) rows, B-frag = zero-padded Wp2. 4 ksteps over K=128.
// N_EDGES = 64 * 9375 exactly.
// ===========================================================================
__global__ __launch_bounds__(256) void edge_pred_kernel(
        const _Float16* __restrict__ UV,
        const int2* __restrict__ pk,
        const int* __restrict__ pdst,
        const _Float16* __restrict__ Wp2b,
        const float* __restrict__ bp2,
        float* __restrict__ out) {
    int t = threadIdx.x;
    int wave = t >> 6;
    int lane = t & 63;
    int row = lane & 15;
    int kgrp = lane >> 4;
    int e0 = blockIdx.x * 64 + wave * 16;

    int2 pv = pk[e0 + row];
    int dn = pdst[e0 + row];
    const _Float16* ubase = &UV[pv.x * 256 + kgrp * 8];
    const _Float16* vbase = &UV[dn * 256 + 128 + kgrp * 8];

    f16x8 au[4], av[4], bf[4];
#pragma unroll
    for (int ks = 0; ks < 4; ++ks) {
        au[ks] = *(const f16x8*)&ubase[ks * 32];
        av[ks] = *(const f16x8*)&vbase[ks * 32];
        bf[ks] = *(const f16x8*)&Wp2b[(ks * 64 + lane) * 8];
    }

    f32x4 acc = (f32x4){0.f, 0.f, 0.f, 0.f};
#pragma unroll
    for (int ks = 0; ks < 4; ++ks) {
        f16x8 z = au[ks] + av[ks];
#pragma unroll
        for (int j = 0; j < 8; ++j) z[j] = z[j] > (_Float16)0 ? z[j] : (_Float16)0;
        acc = __builtin_amdgcn_mfma_f32_16x16x32_f16(z, bf[ks], acc, 0, 0, 0);
    }

    // gather eids for this lane's 4 C-rows (all lanes active for shuffles)
    int eids[4];
#pragma unroll
    for (int r = 0; r < 4; ++r) eids[r] = __shfl(pv.y, kgrp * 4 + r);

    int col = lane & 15;
    if (col < 2) {
        float bb = bp2[col];
#pragma unroll
        for (int r = 0; r < 4; ++r) out[eids[r] * 2 + col] = acc[r] + bb;
    }
}

// ===========================================================================
extern "C" void kernel_launch(void* const* d_in, const int* in_sizes, int n_in,
                              void* d_out, int out_size, void* d_ws, size_t ws_size,
                              hipStream_t stream) {
    const float* x   = (const float*)d_in[0];
    const int*   ei  = (const int*)d_in[1];
    const float* ea  = (const float*)d_in[2];
    const float* We1 = (const float*)d_in[3];
    const float* be1 = (const float*)d_in[4];
    const float* Wl1 = (const float*)d_in[5];
    const float* bl1 = (const float*)d_in[6];
    const float* Wr1 = (const float*)d_in[7];
    const float* br1 = (const float*)d_in[8];
    const float* We2 = (const float*)d_in[9];
    const float* be2 = (const float*)d_in[10];
    const float* Wl2 = (const float*)d_in[11];
    const float* bl2 = (const float*)d_in[12];
    const float* Wr2 = (const float*)d_in[13];
    const float* br2 = (const float*)d_in[14];
    const float* Wp1 = (const float*)d_in[15];
    const float* bp1 = (const float*)d_in[16];
    const float* Wp2 = (const float*)d_in[17];
    const float* bp2 = (const float*)d_in[18];
    float* out = (float*)d_out;

    const int* src = ei;
    const int* dst = ei + N_EDGES;

    char* ws = (char*)d_ws;
    int*   cnt     = (int*)(ws + 0);           // 409600
    int*   scanout = (int*)(ws + 409600);      // 409600 (dead after scan3)
    int*   bsum    = (int*)(ws + 819200);      // 8192
    int*   rowptr  = (int*)(ws + 827392);      // 409600 (N+1 ints)
    int*   cur     = (int*)(ws + 1236992);     // 409600
    int2*  pk      = (int2*)(ws + 1646592);    // 4800512
    float* WeWl1   = (float*)(ws + 6447104);   // 16384
    float* beWl1   = (float*)(ws + 6463488);   // 512
    float* WeWl2   = (float*)(ws + 6464000);   // 16384
    float* beWl2   = (float*)(ws + 6480384);   // 512
    _Float16* eamb = (_Float16*)(ws + 6480896);   // 6.4 MB
    _Float16* xb   = (_Float16*)(ws + 12880896);  // 25.6 MB
    // UV (51.2 MB) aliases xb+meanb (both dead before uv_gemm)
    _Float16* UV   = (_Float16*)(ws + 12880896);
    _Float16* meanb= (_Float16*)(ws + 38480896);  // 25.6 MB
    _Float16* h1b  = (_Float16*)(ws + 64080896);  // 25.6 MB
    _Float16* h2b  = (_Float16*)(ws + 89680896);  // 25.6 MB
    _Float16* Wbs1 = (_Float16*)(ws + 115280896); // 73728
    _Float16* Wbs2 = (_Float16*)(ws + 115354624); // 73728
    _Float16* Wuv  = (_Float16*)(ws + 115428352); // 65536
    int*   pdst    = (int*)(ws + 115493888);      // 2.4 MB
    // Wp2b (4 KB) reuses the scanout region (dead once wp1uv runs)
    _Float16* Wp2b = (_Float16*)(ws + 409600);

    const int EB = (N_EDGES + 255) / 256;

    // ---- CSR build ----
    hipMemsetAsync(cnt, 0, N_NODES * sizeof(int), stream);
    hist_kernel<<<EB, 256, 0, stream>>>(dst, cnt);
    scan1_kernel<<<NBLK, 256, 0, stream>>>(cnt, scanout, bsum);
    scan2_kernel<<<1, 512, 0, stream>>>(bsum);
    scan3_kernel<<<NBLK, 256, 0, stream>>>(cnt, scanout, bsum, rowptr, cur);
    fill_kernel<<<EB, 256, 0, stream>>>(src, dst, cur, pk, pdst);

    // ---- graph-invariant precompute (batched) ----
    wewl2_kernel<<<33, 256, 0, stream>>>(We1, be1, Wl1, We2, be2, Wl2,
                                         WeWl1, beWl1, WeWl2, beWl2);
    xb_kernel<<<(N_NODES * HIDDEN / 2 + 255) / 256, 256, 0, stream>>>(x, xb);
    wbig2_kernel<<<288, 256, 0, stream>>>(Wl1, Wr1, WeWl1, Wbs1,
                                          Wl2, Wr2, WeWl2, Wbs2);
    wp1uv_swizzle_kernel<<<136, 256, 0, stream>>>(Wp1, Wp2, Wuv, Wp2b);

    // ---- layer 1 ----
    agg_kernel_t<true><<<N_NODES / 32, 256, 0, stream>>>(xb, rowptr, pk, ea, meanb, eamb);
    node_gemm_kernel<<<(N_NODES + 63) / 64, 256, 0, stream>>>(
        meanb, xb, eamb, Wbs1, rowptr, bl1, br1, beWl1, h1b);

    // ---- layer 2 ----
    agg_kernel_t<false><<<N_NODES / 32, 256, 0, stream>>>(h1b, rowptr, pk, nullptr, meanb, nullptr);
    node_gemm_kernel<<<(N_NODES + 63) / 64, 256, 0, stream>>>(
        meanb, h1b, eamb, Wbs2, rowptr, bl2, br2, beWl2, h2b);

    // ---- edge predictor: UV decomposition + MFMA edge pass ----
    uv_gemm_kernel<<<(N_NODES + 63) / 64, 256, 0, stream>>>(h2b, Wuv, bp1, UV);
    edge_pred_kernel<<<N_EDGES / 64, 256, 0, stream>>>(UV, pk, pdst, Wp2b, bp2, out);
}